// Round 1
// baseline (5641.715 us; speedup 1.0000x reference)
//
#include <hip/hip_runtime.h>
#include <math.h>

#define BN 50000
#define BE 800000

__device__ __forceinline__ float relu_f(float v) { return fmaxf(v, 0.0f); }
__device__ __forceinline__ float inv_clean(float s) {
    float q = 1.0f / s;
    return isfinite(q) ? q : 0.0f;
}

// ---------------------------------------------------------------------------
// Kernel 1: node encoder  node_emb = relu(x @ W + b)   [BN,2]@[2,64]
// grid = BN*64/256 exactly (50000*64 = 3.2M threads)
// ---------------------------------------------------------------------------
__global__ __launch_bounds__(256) void k_node_enc(
    const float* __restrict__ x, const float* __restrict__ W,
    const float* __restrict__ b, float* __restrict__ node_emb)
{
    int t = blockIdx.x * 256 + threadIdx.x;
    int i = t >> 6, l = t & 63;
    float v = fmaf(x[i*2], W[l], fmaf(x[i*2+1], W[64+l], b[l]));
    node_emb[t] = relu_f(v);
}

// ---------------------------------------------------------------------------
// Kernel 2 (edge pass 1): per edge
//   inv_spacing_emb = relu(clean(1/sp) @ enc2)                (on the fly)
//   d_edge = relu([ne[row], ne[col], ise] @ dW1 + db1) @ dW2 + db2
//   atomic: sumsp[row]+=sp, sumsp[col]+=sp; hjp[row]+=d_edge; hjm[col]+=d_edge
// 4 waves/block, 4 edges per wave-group. dW1/dW2 staged in LDS (~153KB).
// ---------------------------------------------------------------------------
__global__ __launch_bounds__(256) void k_edge1(
    const int* __restrict__ ei, const float* __restrict__ ea,
    const float* __restrict__ node_emb,
    const float* __restrict__ e2w_g, const float* __restrict__ e2b_g,
    const float* __restrict__ dW1, const float* __restrict__ db1,
    const float* __restrict__ dW2, const float* __restrict__ db2,
    float* __restrict__ sumsp, float* __restrict__ hjp, float* __restrict__ hjm)
{
    extern __shared__ float lds[];
    float* w1 = lds;                    // 192*128 = 24576
    float* b1 = w1 + 192*128;           // 128
    float* w2 = b1 + 128;               // 128*64 = 8192
    float* b2 = w2 + 128*64;            // 64
    float* ew = b2 + 64;                // 128
    float* eb = ew + 128;               // 64
    float* xreg = eb + 64;              // 4 waves * 768
    float* hreg = xreg + 4*768;         // 4 waves * 512

    for (int idx = threadIdx.x; idx < 192*128; idx += 256) w1[idx] = dW1[idx];
    for (int idx = threadIdx.x; idx < 128*64; idx += 256)  w2[idx] = dW2[idx];
    if (threadIdx.x < 128) { b1[threadIdx.x] = db1[threadIdx.x]; ew[threadIdx.x] = e2w_g[threadIdx.x]; }
    if (threadIdx.x < 64)  { b2[threadIdx.x] = db2[threadIdx.x]; eb[threadIdx.x] = e2b_g[threadIdx.x]; }
    __syncthreads();

    const int wid = threadIdx.x >> 6, l = threadIdx.x & 63;
    float* xbuf = xreg + wid * 768;
    float* hbuf = hreg + wid * 512;
    const int gw = blockIdx.x * 4 + wid;
    const int nw = gridDim.x * 4;

    for (int g = gw; g < BE/4; g += nw) {
        const int e0 = g * 4;
        int r[4], c[4];
        float s0[4], s1[4];
        #pragma unroll
        for (int e = 0; e < 4; e++) {
            r[e]  = ei[e0+e];
            c[e]  = ei[BE + e0+e];
            s0[e] = ea[(e0+e)*2+0];
            s1[e] = ea[(e0+e)*2+1];
        }
        if (l < 16) {
            int e = l >> 2, wch = l & 3;
            int node = (wch < 2) ? r[e] : c[e];
            float v = (wch & 1) ? s1[e] : s0[e];
            atomicAdd(&sumsp[node*2 + (wch & 1)], v);
        }
        float ar[4], cr[4], ir[4];
        #pragma unroll
        for (int e = 0; e < 4; e++) {
            ar[e] = node_emb[r[e]*64 + l];
            cr[e] = node_emb[c[e]*64 + l];
            float q0 = inv_clean(s0[e]), q1 = inv_clean(s1[e]);
            ir[e] = relu_f(fmaf(q0, ew[l], fmaf(q1, ew[64+l], eb[l])));
        }
        ((float4*)xbuf)[l]       = make_float4(ar[0], ar[1], ar[2], ar[3]);
        ((float4*)xbuf)[64 + l]  = make_float4(cr[0], cr[1], cr[2], cr[3]);
        ((float4*)xbuf)[128 + l] = make_float4(ir[0], ir[1], ir[2], ir[3]);

        float acc0[4] = {0,0,0,0}, acc1[4] = {0,0,0,0};
        #pragma unroll 8
        for (int j = 0; j < 192; j++) {
            float4 xv = ((const float4*)xbuf)[j];
            float2 wv = ((const float2*)(w1 + j*128))[l];
            acc0[0] = fmaf(xv.x, wv.x, acc0[0]);
            acc0[1] = fmaf(xv.y, wv.x, acc0[1]);
            acc0[2] = fmaf(xv.z, wv.x, acc0[2]);
            acc0[3] = fmaf(xv.w, wv.x, acc0[3]);
            acc1[0] = fmaf(xv.x, wv.y, acc1[0]);
            acc1[1] = fmaf(xv.y, wv.y, acc1[1]);
            acc1[2] = fmaf(xv.z, wv.y, acc1[2]);
            acc1[3] = fmaf(xv.w, wv.y, acc1[3]);
        }
        float bb0 = b1[2*l], bb1 = b1[2*l+1];
        #pragma unroll
        for (int e = 0; e < 4; e++) {
            float2 h = make_float2(relu_f(acc0[e]+bb0), relu_f(acc1[e]+bb1));
            ((float2*)(hbuf + e*128))[l] = h;
        }
        float o[4] = {0,0,0,0};
        #pragma unroll 8
        for (int k = 0; k < 128; k++) {
            float wv = w2[k*64 + l];
            o[0] = fmaf(hbuf[0*128+k], wv, o[0]);
            o[1] = fmaf(hbuf[1*128+k], wv, o[1]);
            o[2] = fmaf(hbuf[2*128+k], wv, o[2]);
            o[3] = fmaf(hbuf[3*128+k], wv, o[3]);
        }
        float bo = b2[l];
        #pragma unroll
        for (int e = 0; e < 4; e++) {
            float ov = o[e] + bo;
            atomicAdd(&hjp[r[e]*64 + l], ov);
            atomicAdd(&hjm[c[e]*64 + l], ov);
        }
    }
}

// ---------------------------------------------------------------------------
// Kernel 3 (edge pass 2): per edge
//   se = relu(sp @ enc_edge)          (recomputed, cheap)
//   o1 = mlp([se, hjp[col]]);  o2 = mlp([se, hjm[row]])   (shared hW1/hW2)
//   atomic: jac1[col]+=o1; jac2[row]+=o2
// ---------------------------------------------------------------------------
__global__ __launch_bounds__(256) void k_edge2(
    const int* __restrict__ ei, const float* __restrict__ ea,
    const float* __restrict__ hjp, const float* __restrict__ hjm,
    const float* __restrict__ eew_g, const float* __restrict__ eeb_g,
    const float* __restrict__ hW1, const float* __restrict__ hb1,
    const float* __restrict__ hW2, const float* __restrict__ hb2,
    float* __restrict__ jac1, float* __restrict__ jac2)
{
    extern __shared__ float lds[];
    float* w1 = lds;                 // 128*128 = 16384
    float* b1 = w1 + 128*128;        // 128
    float* w2 = b1 + 128;            // 8192
    float* b2 = w2 + 128*64;         // 64
    float* ew = b2 + 64;             // 128
    float* eb = ew + 128;            // 64
    float* base = eb + 64;           // 4 waves * 2048 (x1,x2,h1,h2 @512)

    for (int idx = threadIdx.x; idx < 128*128; idx += 256) w1[idx] = hW1[idx];
    for (int idx = threadIdx.x; idx < 128*64; idx += 256)  w2[idx] = hW2[idx];
    if (threadIdx.x < 128) { b1[threadIdx.x] = hb1[threadIdx.x]; ew[threadIdx.x] = eew_g[threadIdx.x]; }
    if (threadIdx.x < 64)  { b2[threadIdx.x] = hb2[threadIdx.x]; eb[threadIdx.x] = eeb_g[threadIdx.x]; }
    __syncthreads();

    const int wid = threadIdx.x >> 6, l = threadIdx.x & 63;
    float* x1 = base + wid*2048;
    float* x2 = x1 + 512;
    float* h1 = x2 + 512;
    float* h2 = h1 + 512;
    const int gw = blockIdx.x * 4 + wid;
    const int nw = gridDim.x * 4;

    for (int g = gw; g < BE/4; g += nw) {
        const int e0 = g * 4;
        int r[4], c[4];
        float se[4], pa[4], pb[4];
        #pragma unroll
        for (int e = 0; e < 4; e++) {
            r[e] = ei[e0+e];
            c[e] = ei[BE + e0+e];
            float sp0 = ea[(e0+e)*2+0], sp1 = ea[(e0+e)*2+1];
            se[e] = relu_f(fmaf(sp0, ew[l], fmaf(sp1, ew[64+l], eb[l])));
            pa[e] = hjp[c[e]*64 + l];
            pb[e] = hjm[r[e]*64 + l];
        }
        ((float4*)x1)[l]      = make_float4(se[0], se[1], se[2], se[3]);
        ((float4*)x1)[64 + l] = make_float4(pa[0], pa[1], pa[2], pa[3]);
        ((float4*)x2)[l]      = make_float4(se[0], se[1], se[2], se[3]);
        ((float4*)x2)[64 + l] = make_float4(pb[0], pb[1], pb[2], pb[3]);

        float a0[4]={0,0,0,0}, a1[4]={0,0,0,0}, b0v[4]={0,0,0,0}, b1v[4]={0,0,0,0};
        #pragma unroll 8
        for (int j = 0; j < 128; j++) {
            float2 wv = ((const float2*)(w1 + j*128))[l];
            float4 xa = ((const float4*)x1)[j];
            float4 xb = ((const float4*)x2)[j];
            a0[0]=fmaf(xa.x,wv.x,a0[0]); a0[1]=fmaf(xa.y,wv.x,a0[1]);
            a0[2]=fmaf(xa.z,wv.x,a0[2]); a0[3]=fmaf(xa.w,wv.x,a0[3]);
            a1[0]=fmaf(xa.x,wv.y,a1[0]); a1[1]=fmaf(xa.y,wv.y,a1[1]);
            a1[2]=fmaf(xa.z,wv.y,a1[2]); a1[3]=fmaf(xa.w,wv.y,a1[3]);
            b0v[0]=fmaf(xb.x,wv.x,b0v[0]); b0v[1]=fmaf(xb.y,wv.x,b0v[1]);
            b0v[2]=fmaf(xb.z,wv.x,b0v[2]); b0v[3]=fmaf(xb.w,wv.x,b0v[3]);
            b1v[0]=fmaf(xb.x,wv.y,b1v[0]); b1v[1]=fmaf(xb.y,wv.y,b1v[1]);
            b1v[2]=fmaf(xb.z,wv.y,b1v[2]); b1v[3]=fmaf(xb.w,wv.y,b1v[3]);
        }
        float bb0 = b1[2*l], bb1 = b1[2*l+1];
        #pragma unroll
        for (int e = 0; e < 4; e++) {
            ((float2*)(h1 + e*128))[l] = make_float2(relu_f(a0[e]+bb0), relu_f(a1[e]+bb1));
            ((float2*)(h2 + e*128))[l] = make_float2(relu_f(b0v[e]+bb0), relu_f(b1v[e]+bb1));
        }
        float oA[4]={0,0,0,0}, oB[4]={0,0,0,0};
        #pragma unroll 8
        for (int k = 0; k < 128; k++) {
            float wv = w2[k*64 + l];
            oA[0]=fmaf(h1[0*128+k],wv,oA[0]); oA[1]=fmaf(h1[1*128+k],wv,oA[1]);
            oA[2]=fmaf(h1[2*128+k],wv,oA[2]); oA[3]=fmaf(h1[3*128+k],wv,oA[3]);
            oB[0]=fmaf(h2[0*128+k],wv,oB[0]); oB[1]=fmaf(h2[1*128+k],wv,oB[1]);
            oB[2]=fmaf(h2[2*128+k],wv,oB[2]); oB[3]=fmaf(h2[3*128+k],wv,oB[3]);
        }
        float bo = b2[l];
        #pragma unroll
        for (int e = 0; e < 4; e++) {
            atomicAdd(&jac1[c[e]*64 + l], oA[e] + bo);
            atomicAdd(&jac2[r[e]*64 + l], oB[e] + bo);
        }
    }
}

// ---------------------------------------------------------------------------
// Kernel 4/5 (node MLP template): out = relu([A_i, B_i, ide_i]@W1+b1)@W2+b2
// ide recomputed from sumsp via enc2. Used for jac (A=jac1,B=jac2) and
// hess (A=hjp,B=hjm). Output may alias A (read-before-write per wave).
// ---------------------------------------------------------------------------
__global__ __launch_bounds__(256) void k_node_mlp(
    const float* __restrict__ A, const float* __restrict__ Bv,
    const float* __restrict__ sumsp,
    const float* __restrict__ e2w_g, const float* __restrict__ e2b_g,
    const float* __restrict__ W1g, const float* __restrict__ b1g,
    const float* __restrict__ W2g, const float* __restrict__ b2g,
    float* __restrict__ outp)
{
    extern __shared__ float lds[];
    float* w1 = lds;                    // 24576
    float* b1 = w1 + 192*128;
    float* w2 = b1 + 128;               // 8192
    float* b2 = w2 + 128*64;
    float* ew = b2 + 64;
    float* eb = ew + 128;
    float* xreg = eb + 64;
    float* hreg = xreg + 4*768;

    for (int idx = threadIdx.x; idx < 192*128; idx += 256) w1[idx] = W1g[idx];
    for (int idx = threadIdx.x; idx < 128*64; idx += 256)  w2[idx] = W2g[idx];
    if (threadIdx.x < 128) { b1[threadIdx.x] = b1g[threadIdx.x]; ew[threadIdx.x] = e2w_g[threadIdx.x]; }
    if (threadIdx.x < 64)  { b2[threadIdx.x] = b2g[threadIdx.x]; eb[threadIdx.x] = e2b_g[threadIdx.x]; }
    __syncthreads();

    const int wid = threadIdx.x >> 6, l = threadIdx.x & 63;
    float* xbuf = xreg + wid * 768;
    float* hbuf = hreg + wid * 512;
    const int gw = blockIdx.x * 4 + wid;
    const int nw = gridDim.x * 4;

    for (int g = gw; g < BN/4; g += nw) {
        const int i0 = g * 4;
        float av[4], bv[4], iv[4];
        #pragma unroll
        for (int e = 0; e < 4; e++) {
            int i = i0 + e;
            av[e] = A[i*64 + l];
            bv[e] = Bv[i*64 + l];
            float q0 = inv_clean(sumsp[i*2+0]);
            float q1 = inv_clean(sumsp[i*2+1]);
            iv[e] = relu_f(fmaf(q0, ew[l], fmaf(q1, ew[64+l], eb[l])));
        }
        ((float4*)xbuf)[l]       = make_float4(av[0], av[1], av[2], av[3]);
        ((float4*)xbuf)[64 + l]  = make_float4(bv[0], bv[1], bv[2], bv[3]);
        ((float4*)xbuf)[128 + l] = make_float4(iv[0], iv[1], iv[2], iv[3]);

        float acc0[4] = {0,0,0,0}, acc1[4] = {0,0,0,0};
        #pragma unroll 8
        for (int j = 0; j < 192; j++) {
            float4 xv = ((const float4*)xbuf)[j];
            float2 wv = ((const float2*)(w1 + j*128))[l];
            acc0[0] = fmaf(xv.x, wv.x, acc0[0]);
            acc0[1] = fmaf(xv.y, wv.x, acc0[1]);
            acc0[2] = fmaf(xv.z, wv.x, acc0[2]);
            acc0[3] = fmaf(xv.w, wv.x, acc0[3]);
            acc1[0] = fmaf(xv.x, wv.y, acc1[0]);
            acc1[1] = fmaf(xv.y, wv.y, acc1[1]);
            acc1[2] = fmaf(xv.z, wv.y, acc1[2]);
            acc1[3] = fmaf(xv.w, wv.y, acc1[3]);
        }
        float bb0 = b1[2*l], bb1 = b1[2*l+1];
        #pragma unroll
        for (int e = 0; e < 4; e++) {
            ((float2*)(hbuf + e*128))[l] = make_float2(relu_f(acc0[e]+bb0), relu_f(acc1[e]+bb1));
        }
        float o[4] = {0,0,0,0};
        #pragma unroll 8
        for (int k = 0; k < 128; k++) {
            float wv = w2[k*64 + l];
            o[0] = fmaf(hbuf[0*128+k], wv, o[0]);
            o[1] = fmaf(hbuf[1*128+k], wv, o[1]);
            o[2] = fmaf(hbuf[2*128+k], wv, o[2]);
            o[3] = fmaf(hbuf[3*128+k], wv, o[3]);
        }
        float bo = b2[l];
        #pragma unroll
        for (int e = 0; e < 4; e++) outp[(i0+e)*64 + l] = o[e] + bo;
    }
}

// ---------------------------------------------------------------------------
// Kernel 6 (final): res = relu([ne, jac, glob_emb[batch], hess]@nW1+nb1)@nW2+nb2
//                   out = node_attr * (res @ decW + decb)
// nW1 staged in LDS (131KB); nW2 streamed from L2 (32KB, hot).
// ---------------------------------------------------------------------------
__global__ __launch_bounds__(256) void k_node_final(
    const float* __restrict__ node_emb, const float* __restrict__ jacv,
    const float* __restrict__ hessv,
    const int* __restrict__ batch, const float* __restrict__ ga,
    const float* __restrict__ gw_g, const float* __restrict__ gb_g,
    const float* __restrict__ nW1, const float* __restrict__ nb1,
    const float* __restrict__ nW2, const float* __restrict__ nb2,
    const float* __restrict__ decW, const float* __restrict__ decb,
    const float* __restrict__ node_attr, float* __restrict__ outp)
{
    extern __shared__ float lds[];
    float* w1 = lds;                    // 256*128 = 32768
    float* b1 = w1 + 256*128;           // 128
    float* b2 = b1 + 128;               // 64
    float* gw = b2 + 64;                // 128
    float* gb = gw + 128;               // 64
    float* dw = gb + 64;                // 128
    float* db = dw + 128;               // 2 (+2 pad)
    float* xreg = db + 4;               // 4 waves * 1024
    float* hreg = xreg + 4*1024;        // 4 waves * 512

    for (int idx = threadIdx.x; idx < 256*128; idx += 256) w1[idx] = nW1[idx];
    if (threadIdx.x < 128) { b1[threadIdx.x] = nb1[threadIdx.x]; gw[threadIdx.x] = gw_g[threadIdx.x]; dw[threadIdx.x] = decW[threadIdx.x]; }
    if (threadIdx.x < 64)  { b2[threadIdx.x] = nb2[threadIdx.x]; gb[threadIdx.x] = gb_g[threadIdx.x]; }
    if (threadIdx.x < 2)   { db[threadIdx.x] = decb[threadIdx.x]; }
    __syncthreads();

    const int wid = threadIdx.x >> 6, l = threadIdx.x & 63;
    float* xbuf = xreg + wid * 1024;
    float* hbuf = hreg + wid * 512;
    const int gwv = blockIdx.x * 4 + wid;
    const int nw = gridDim.x * 4;

    for (int g = gwv; g < BN/4; g += nw) {
        const int i0 = g * 4;
        float ne[4], jv[4], ge[4], hv[4];
        #pragma unroll
        for (int e = 0; e < 4; e++) {
            int i = i0 + e;
            ne[e] = node_emb[i*64 + l];
            jv[e] = jacv[i*64 + l];
            hv[e] = hessv[i*64 + l];
            int gi = batch[i];
            ge[e] = relu_f(fmaf(ga[gi*2], gw[l], fmaf(ga[gi*2+1], gw[64+l], gb[l])));
        }
        ((float4*)xbuf)[l]       = make_float4(ne[0], ne[1], ne[2], ne[3]);
        ((float4*)xbuf)[64 + l]  = make_float4(jv[0], jv[1], jv[2], jv[3]);
        ((float4*)xbuf)[128 + l] = make_float4(ge[0], ge[1], ge[2], ge[3]);
        ((float4*)xbuf)[192 + l] = make_float4(hv[0], hv[1], hv[2], hv[3]);

        float acc0[4] = {0,0,0,0}, acc1[4] = {0,0,0,0};
        #pragma unroll 8
        for (int j = 0; j < 256; j++) {
            float4 xv = ((const float4*)xbuf)[j];
            float2 wv = ((const float2*)(w1 + j*128))[l];
            acc0[0] = fmaf(xv.x, wv.x, acc0[0]);
            acc0[1] = fmaf(xv.y, wv.x, acc0[1]);
            acc0[2] = fmaf(xv.z, wv.x, acc0[2]);
            acc0[3] = fmaf(xv.w, wv.x, acc0[3]);
            acc1[0] = fmaf(xv.x, wv.y, acc1[0]);
            acc1[1] = fmaf(xv.y, wv.y, acc1[1]);
            acc1[2] = fmaf(xv.z, wv.y, acc1[2]);
            acc1[3] = fmaf(xv.w, wv.y, acc1[3]);
        }
        float bb0 = b1[2*l], bb1 = b1[2*l+1];
        #pragma unroll
        for (int e = 0; e < 4; e++) {
            ((float2*)(hbuf + e*128))[l] = make_float2(relu_f(acc0[e]+bb0), relu_f(acc1[e]+bb1));
        }
        float o[4] = {0,0,0,0};
        #pragma unroll 8
        for (int k = 0; k < 128; k++) {
            float wv = nW2[k*64 + l];    // streamed from L2 (32KB, hot)
            o[0] = fmaf(hbuf[0*128+k], wv, o[0]);
            o[1] = fmaf(hbuf[1*128+k], wv, o[1]);
            o[2] = fmaf(hbuf[2*128+k], wv, o[2]);
            o[3] = fmaf(hbuf[3*128+k], wv, o[3]);
        }
        float bo = b2[l];
        #pragma unroll
        for (int e = 0; e < 4; e++) hbuf[e*128 + l] = o[e] + bo;   // res rows

        // decoder: out[i,j] = node_attr[i,j] * (sum_k res[k]*decW[k,j] + decb[j])
        int e2 = l >> 4, sub = l & 15, j2 = sub >> 3, part = sub & 7;
        float s = 0.0f;
        #pragma unroll
        for (int kk = 0; kk < 8; kk++) {
            int k = part*8 + kk;
            s = fmaf(hbuf[e2*128 + k], dw[k*2 + j2], s);
        }
        s += __shfl_xor(s, 1);
        s += __shfl_xor(s, 2);
        s += __shfl_xor(s, 4);
        if (part == 0) {
            int i = i0 + e2;
            outp[i*2 + j2] = (s + db[j2]) * node_attr[i*2 + j2];
        }
    }
}

// ---------------------------------------------------------------------------
extern "C" void kernel_launch(void* const* d_in, const int* in_sizes, int n_in,
                              void* d_out, int out_size, void* d_ws, size_t ws_size,
                              hipStream_t stream) {
    const float* x          = (const float*)d_in[0];
    const int*   ei         = (const int*)  d_in[1];
    const int*   batch      = (const int*)  d_in[2];
    const float* node_attr  = (const float*)d_in[3];
    const float* edge_attr  = (const float*)d_in[4];
    const float* glob_attr  = (const float*)d_in[5];
    const float* enc_node_W = (const float*)d_in[6];
    const float* enc_node_b = (const float*)d_in[7];
    const float* enc_edge_W = (const float*)d_in[8];
    const float* enc_edge_b = (const float*)d_in[9];
    const float* enc_glob_W = (const float*)d_in[10];
    const float* enc_glob_b = (const float*)d_in[11];
    const float* enc2_W     = (const float*)d_in[12];
    const float* enc2_b     = (const float*)d_in[13];
    const float* dW1 = (const float*)d_in[14]; const float* db1 = (const float*)d_in[15];
    const float* dW2 = (const float*)d_in[16]; const float* db2 = (const float*)d_in[17];
    const float* hW1 = (const float*)d_in[18]; const float* hb1 = (const float*)d_in[19];
    const float* hW2 = (const float*)d_in[20]; const float* hb2 = (const float*)d_in[21];
    const float* jW1 = (const float*)d_in[22]; const float* jb1 = (const float*)d_in[23];
    const float* jW2 = (const float*)d_in[24]; const float* jb2 = (const float*)d_in[25];
    const float* sW1 = (const float*)d_in[26]; const float* sb1 = (const float*)d_in[27];
    const float* sW2 = (const float*)d_in[28]; const float* sb2 = (const float*)d_in[29];
    const float* nW1 = (const float*)d_in[30]; const float* nb1 = (const float*)d_in[31];
    const float* nW2 = (const float*)d_in[32]; const float* nb2 = (const float*)d_in[33];
    const float* decW = (const float*)d_in[34]; const float* decb = (const float*)d_in[35];

    float* ws = (float*)d_ws;
    float* node_emb = ws;                   // 3.2M floats
    float* hjp   = node_emb + 3200000;      // 3.2M  (later holds hess)
    float* hjm   = hjp + 3200000;           // 3.2M
    float* jac1  = hjm + 3200000;           // 3.2M  (later holds jac)
    float* jac2  = jac1 + 3200000;          // 3.2M
    float* sumsp = jac2 + 3200000;          // 100K

    // zero accumulators (hjp, hjm, jac1, jac2 are contiguous)
    hipMemsetAsync(hjp, 0, (size_t)4*3200000*sizeof(float), stream);
    hipMemsetAsync(sumsp, 0, (size_t)100000*sizeof(float), stream);

    k_node_enc<<<12500, 256, 0, stream>>>(x, enc_node_W, enc_node_b, node_emb);

    size_t lds1 = 38272u * sizeof(float);   // 153,088 B
    k_edge1<<<256, 256, lds1, stream>>>(ei, edge_attr, node_emb, enc2_W, enc2_b,
                                        dW1, db1, dW2, db2, sumsp, hjp, hjm);

    size_t lds2 = 33152u * sizeof(float);   // 132,608 B
    k_edge2<<<256, 256, lds2, stream>>>(ei, edge_attr, hjp, hjm,
                                        enc_edge_W, enc_edge_b,
                                        hW1, hb1, hW2, hb2, jac1, jac2);

    size_t lds3 = 38272u * sizeof(float);
    // jac = mlp([jac1, jac2, ide]) -> written in place over jac1
    k_node_mlp<<<256, 256, lds3, stream>>>(jac1, jac2, sumsp, enc2_W, enc2_b,
                                           jW1, jb1, jW2, jb2, jac1);
    // hess = mlp([hjp, hjm, ide]) -> written in place over hjp
    k_node_mlp<<<256, 256, lds3, stream>>>(hjp, hjm, sumsp, enc2_W, enc2_b,
                                           sW1, sb1, sW2, sb2, hjp);

    size_t lds4 = 39428u * sizeof(float);   // 157,712 B
    k_node_final<<<256, 256, lds4, stream>>>(node_emb, jac1, hjp,
                                             batch, glob_attr, enc_glob_W, enc_glob_b,
                                             nW1, nb1, nW2, nb2, decW, decb,
                                             node_attr, (float*)d_out);
}

// Round 2
// 2138.972 us; speedup vs baseline: 2.6376x; 2.6376x over previous
//
#include <hip/hip_runtime.h>
#include <math.h>

#define BN 50000
#define BE 800000

__device__ __forceinline__ float relu_f(float v) { return fmaxf(v, 0.0f); }
__device__ __forceinline__ float inv_clean(float s) {
    float q = 1.0f / s;
    return isfinite(q) ? q : 0.0f;
}
__device__ __forceinline__ float inv_clean_fast(float s) {
    float q = __builtin_amdgcn_rcpf(s);
    return isfinite(q) ? q : 0.0f;
}

// ===========================================================================
// Kernel 1: node encoder  node_emb = relu(x @ W + b)   [BN,2]@[2,64]
// ===========================================================================
__global__ __launch_bounds__(256) void k_node_enc(
    const float* __restrict__ x, const float* __restrict__ W,
    const float* __restrict__ b, float* __restrict__ node_emb)
{
    int t = blockIdx.x * 256 + threadIdx.x;
    int i = t >> 6, l = t & 63;
    float v = fmaf(x[i*2], W[l], fmaf(x[i*2+1], W[64+l], b[l]));
    node_emb[t] = relu_f(v);
}

// ===========================================================================
// FAST PATH KERNELS (linear-split pipeline)
// ===========================================================================

// k_uv: u[n] = ne[n] @ dW1[0:64,:],  v[n] = ne[n] @ dW1[64:128,:]
// Treated as one [BN,64] x [64,256] GEMM; lane l covers output cols 4l..4l+3
// of the concatenated [u|v] output (l<32 -> u, l>=32 -> v).
__global__ __launch_bounds__(256, 2) void k_uv(
    const float* __restrict__ ne, const float* __restrict__ dW1,
    float* __restrict__ u, float* __restrict__ v)
{
    extern __shared__ float lds[];
    float4* wpk = (float4*)lds;              // [64 j][64 l] float4 = 16384 f
    float*  xbase = lds + 16384;             // 4 waves * 512 f

    for (int idx = threadIdx.x; idx < 64*64; idx += 256) {
        int j = idx >> 6, l = idx & 63;
        float4 w;
        if (l < 32) w = ((const float4*)(dW1 + j*128))[l];
        else        w = ((const float4*)(dW1 + (64+j)*128))[l-32];
        wpk[idx] = w;
    }
    __syncthreads();

    const int wid = threadIdx.x >> 6, l = threadIdx.x & 63;
    float* xb = xbase + wid * 512;
    float4* xb4 = (float4*)xb;
    const int gw = blockIdx.x * 4 + wid;
    const int nw = gridDim.x * 4;

    for (int g = gw; g < BN/8; g += nw) {
        const int n0 = g * 8;
        // transpose-gather ne rows -> xb[j][e]
        const int q = l >> 5;           // node-quad
        #pragma unroll
        for (int r = 0; r < 2; r++) {
            int j = (l & 31) + 32*r;
            float v0 = ne[(n0 + q*4 + 0)*64 + j];
            float v1 = ne[(n0 + q*4 + 1)*64 + j];
            float v2 = ne[(n0 + q*4 + 2)*64 + j];
            float v3 = ne[(n0 + q*4 + 3)*64 + j];
            xb4[j*2 + q] = make_float4(v0, v1, v2, v3);
        }
        float4 acc[8];
        #pragma unroll
        for (int e = 0; e < 8; e++) acc[e] = make_float4(0,0,0,0);
        #pragma unroll 8
        for (int j = 0; j < 64; j++) {
            float4 wq = wpk[j*64 + l];
            float4 xa = xb4[j*2 + 0];
            float4 xc = xb4[j*2 + 1];
            acc[0].x = fmaf(xa.x, wq.x, acc[0].x); acc[0].y = fmaf(xa.x, wq.y, acc[0].y);
            acc[0].z = fmaf(xa.x, wq.z, acc[0].z); acc[0].w = fmaf(xa.x, wq.w, acc[0].w);
            acc[1].x = fmaf(xa.y, wq.x, acc[1].x); acc[1].y = fmaf(xa.y, wq.y, acc[1].y);
            acc[1].z = fmaf(xa.y, wq.z, acc[1].z); acc[1].w = fmaf(xa.y, wq.w, acc[1].w);
            acc[2].x = fmaf(xa.z, wq.x, acc[2].x); acc[2].y = fmaf(xa.z, wq.y, acc[2].y);
            acc[2].z = fmaf(xa.z, wq.z, acc[2].z); acc[2].w = fmaf(xa.z, wq.w, acc[2].w);
            acc[3].x = fmaf(xa.w, wq.x, acc[3].x); acc[3].y = fmaf(xa.w, wq.y, acc[3].y);
            acc[3].z = fmaf(xa.w, wq.z, acc[3].z); acc[3].w = fmaf(xa.w, wq.w, acc[3].w);
            acc[4].x = fmaf(xc.x, wq.x, acc[4].x); acc[4].y = fmaf(xc.x, wq.y, acc[4].y);
            acc[4].z = fmaf(xc.x, wq.z, acc[4].z); acc[4].w = fmaf(xc.x, wq.w, acc[4].w);
            acc[5].x = fmaf(xc.y, wq.x, acc[5].x); acc[5].y = fmaf(xc.y, wq.y, acc[5].y);
            acc[5].z = fmaf(xc.y, wq.z, acc[5].z); acc[5].w = fmaf(xc.y, wq.w, acc[5].w);
            acc[6].x = fmaf(xc.z, wq.x, acc[6].x); acc[6].y = fmaf(xc.z, wq.y, acc[6].y);
            acc[6].z = fmaf(xc.z, wq.z, acc[6].z); acc[6].w = fmaf(xc.z, wq.w, acc[6].w);
            acc[7].x = fmaf(xc.w, wq.x, acc[7].x); acc[7].y = fmaf(xc.w, wq.y, acc[7].y);
            acc[7].z = fmaf(xc.w, wq.z, acc[7].z); acc[7].w = fmaf(xc.w, wq.w, acc[7].w);
        }
        float* dst = (l < 32) ? (u + 4*l) : (v + 4*(l-32));
        #pragma unroll
        for (int e = 0; e < 8; e++) {
            *(float4*)(dst + (size_t)(n0+e)*128) = acc[e];
        }
    }
}

// k_tptm: tp[n] = hjp[n] @ hW1[64:128,:], tm[n] = hjm[n] @ hW1[64:128,:]
// virtual groups: vg < BN/8 -> (hjp,tp); else (hjm,tm). lane covers cols 2l,2l+1
__global__ __launch_bounds__(256, 2) void k_tptm(
    const float* __restrict__ hjp, const float* __restrict__ hjm,
    const float* __restrict__ hW1,
    float* __restrict__ tp, float* __restrict__ tm)
{
    extern __shared__ float lds[];
    float4* wpk = (float4*)lds;              // [32 j2][64 l] float4 = 8192 f
    float*  xbase = lds + 8192;              // 4 waves * 512 f

    for (int idx = threadIdx.x; idx < 32*64; idx += 256) {
        int j2 = idx >> 6, l = idx & 63;
        float2 lo = ((const float2*)(hW1 + (64 + 2*j2)*128))[l];
        float2 hi = ((const float2*)(hW1 + (64 + 2*j2 + 1)*128))[l];
        wpk[idx] = make_float4(lo.x, lo.y, hi.x, hi.y);
    }
    __syncthreads();

    const int wid = threadIdx.x >> 6, l = threadIdx.x & 63;
    float* xb = xbase + wid * 512;
    float4* xb4 = (float4*)xb;
    const int gw = blockIdx.x * 4 + wid;
    const int nw = gridDim.x * 4;
    const int NG = BN/8;

    for (int vg = gw; vg < 2*NG; vg += nw) {
        const float* in  = (vg < NG) ? hjp : hjm;
        float*       out = (vg < NG) ? tp  : tm;
        const int n0 = ((vg < NG) ? vg : vg - NG) * 8;
        const int q = l >> 5;
        #pragma unroll
        for (int r = 0; r < 2; r++) {
            int j = (l & 31) + 32*r;
            float v0 = in[(n0 + q*4 + 0)*64 + j];
            float v1 = in[(n0 + q*4 + 1)*64 + j];
            float v2 = in[(n0 + q*4 + 2)*64 + j];
            float v3 = in[(n0 + q*4 + 3)*64 + j];
            xb4[j*2 + q] = make_float4(v0, v1, v2, v3);
        }
        float a0[8] = {0,0,0,0,0,0,0,0}, a1[8] = {0,0,0,0,0,0,0,0};
        #pragma unroll 8
        for (int j2 = 0; j2 < 32; j2++) {
            float4 wq = wpk[j2*64 + l];
            float4 xa = xb4[(2*j2)*2 + 0];
            float4 xbv = xb4[(2*j2)*2 + 1];
            float4 xc = xb4[(2*j2+1)*2 + 0];
            float4 xd = xb4[(2*j2+1)*2 + 1];
            a0[0] = fmaf(xa.x, wq.x, fmaf(xc.x, wq.z, a0[0]));
            a1[0] = fmaf(xa.x, wq.y, fmaf(xc.x, wq.w, a1[0]));
            a0[1] = fmaf(xa.y, wq.x, fmaf(xc.y, wq.z, a0[1]));
            a1[1] = fmaf(xa.y, wq.y, fmaf(xc.y, wq.w, a1[1]));
            a0[2] = fmaf(xa.z, wq.x, fmaf(xc.z, wq.z, a0[2]));
            a1[2] = fmaf(xa.z, wq.y, fmaf(xc.z, wq.w, a1[2]));
            a0[3] = fmaf(xa.w, wq.x, fmaf(xc.w, wq.z, a0[3]));
            a1[3] = fmaf(xa.w, wq.y, fmaf(xc.w, wq.w, a1[3]));
            a0[4] = fmaf(xbv.x, wq.x, fmaf(xd.x, wq.z, a0[4]));
            a1[4] = fmaf(xbv.x, wq.y, fmaf(xd.x, wq.w, a1[4]));
            a0[5] = fmaf(xbv.y, wq.x, fmaf(xd.y, wq.z, a0[5]));
            a1[5] = fmaf(xbv.y, wq.y, fmaf(xd.y, wq.w, a1[5]));
            a0[6] = fmaf(xbv.z, wq.x, fmaf(xd.z, wq.z, a0[6]));
            a1[6] = fmaf(xbv.z, wq.y, fmaf(xd.z, wq.w, a1[6]));
            a0[7] = fmaf(xbv.w, wq.x, fmaf(xd.w, wq.z, a0[7]));
            a1[7] = fmaf(xbv.w, wq.y, fmaf(xd.w, wq.w, a1[7]));
        }
        #pragma unroll
        for (int e = 0; e < 8; e++) {
            *(float2*)(out + (size_t)(n0+e)*128 + 2*l) = make_float2(a0[e], a1[e]);
        }
    }
}

// k_edge1f: per edge: t = u[row] + v[col] + Wc*ise + b1; h=relu(t); o=W2*h+b2
//           atomics: hjp[row]+=o, hjm[col]+=o, sumsp += spacing
__global__ __launch_bounds__(256, 2) void k_edge1f(
    const int* __restrict__ ei, const float* __restrict__ ea,
    const float* __restrict__ u, const float* __restrict__ v,
    const float* __restrict__ e2w, const float* __restrict__ e2b,
    const float* __restrict__ dW1, const float* __restrict__ db1,
    const float* __restrict__ dW2, const float* __restrict__ db2,
    float* __restrict__ sumsp, float* __restrict__ hjp, float* __restrict__ hjm)
{
    extern __shared__ float lds[];
    float4* w1pk = (float4*)lds;                 // [32 j2][64 l] = 8192 f
    float4* w2pk = (float4*)(lds + 8192);        // [32 k4][64 l] = 8192 f
    float*  bufbase = lds + 16384;               // 4 waves * 1024 f

    for (int idx = threadIdx.x; idx < 32*64; idx += 256) {
        int j2 = idx >> 6, ll = idx & 63;
        float2 lo = ((const float2*)(dW1 + (128 + 2*j2)*128))[ll];
        float2 hi = ((const float2*)(dW1 + (128 + 2*j2 + 1)*128))[ll];
        w1pk[idx] = make_float4(lo.x, lo.y, hi.x, hi.y);
    }
    for (int idx = threadIdx.x; idx < 32*64; idx += 256) {
        int k4 = idx >> 6, ll = idx & 63;
        w2pk[idx] = make_float4(dW2[(4*k4+0)*64+ll], dW2[(4*k4+1)*64+ll],
                                dW2[(4*k4+2)*64+ll], dW2[(4*k4+3)*64+ll]);
    }
    __syncthreads();

    const int wid = threadIdx.x >> 6, l = threadIdx.x & 63;
    float* buf = bufbase + wid * 1024;
    float4* buf4 = (float4*)buf;

    // per-lane constants
    const int jA = l >> 1;
    const int eh = l & 1;
    const float ewA0 = e2w[jA],      ewB0 = e2w[64+jA],    eb0v = e2b[jA];
    const float ewA1 = e2w[jA+32],   ewB1 = e2w[96+jA],    eb1v = e2b[jA+32];
    const float b1a = db1[2*l], b1b = db1[2*l+1];
    const float b2r = db2[l];

    const int gw = blockIdx.x * 4 + wid;
    const int nw = gridDim.x * 4;

    for (int g = gw; g < BE/8; g += nw) {
        const int e0 = g * 8;
        int4 r01 = *(const int4*)(ei + e0);
        int4 r2  = *(const int4*)(ei + e0 + 4);
        int4 c01 = *(const int4*)(ei + BE + e0);
        int4 c2  = *(const int4*)(ei + BE + e0 + 4);
        float4 sv0 = ((const float4*)(ea + 2*e0))[0];
        float4 sv1 = ((const float4*)(ea + 2*e0))[1];
        float4 sv2 = ((const float4*)(ea + 2*e0))[2];
        float4 sv3 = ((const float4*)(ea + 2*e0))[3];

        // sumsp atomics (lanes 0..31: e = l>>2, wch = l&3)
        if (l < 32) {
            int e = l >> 2, wch = l & 3;
            int4 rA = (e & 4) ? r2 : r01;
            int rx = (e & 2) ? ((e & 1) ? rA.w : rA.z) : ((e & 1) ? rA.y : rA.x);
            int4 cA = (e & 4) ? c2 : c01;
            int cx = (e & 2) ? ((e & 1) ? cA.w : cA.z) : ((e & 1) ? cA.y : cA.x);
            float4 sA = (e & 4) ? ((e & 2) ? sv3 : sv2) : ((e & 2) ? sv1 : sv0);
            float s0e = (e & 1) ? sA.z : sA.x;
            float s1e = (e & 1) ? sA.w : sA.y;
            int node = (wch < 2) ? rx : cx;
            int comp = wch & 1;
            float val = comp ? s1e : s0e;
            atomicAdd(&sumsp[node*2 + comp], val);
        }

        // ise -> transposed xbuf: lane handles j = jA(+32), edges 4*eh..4*eh+3
        {
            float4 svA = eh ? sv2 : sv0;
            float4 svB = eh ? sv3 : sv1;
            float q00 = inv_clean_fast(svA.x), q10 = inv_clean_fast(svA.y);
            float q01 = inv_clean_fast(svA.z), q11 = inv_clean_fast(svA.w);
            float q02 = inv_clean_fast(svB.x), q12 = inv_clean_fast(svB.y);
            float q03 = inv_clean_fast(svB.z), q13 = inv_clean_fast(svB.w);
            float4 p0, p1;
            p0.x = relu_f(fmaf(q00, ewA0, fmaf(q10, ewB0, eb0v)));
            p0.y = relu_f(fmaf(q01, ewA0, fmaf(q11, ewB0, eb0v)));
            p0.z = relu_f(fmaf(q02, ewA0, fmaf(q12, ewB0, eb0v)));
            p0.w = relu_f(fmaf(q03, ewA0, fmaf(q13, ewB0, eb0v)));
            p1.x = relu_f(fmaf(q00, ewA1, fmaf(q10, ewB1, eb1v)));
            p1.y = relu_f(fmaf(q01, ewA1, fmaf(q11, ewB1, eb1v)));
            p1.z = relu_f(fmaf(q02, ewA1, fmaf(q12, ewB1, eb1v)));
            p1.w = relu_f(fmaf(q03, ewA1, fmaf(q13, ewB1, eb1v)));
            buf4[jA*2 + eh]      = p0;
            buf4[(jA+32)*2 + eh] = p1;
        }

        // gather u[row], v[col]; init accumulators with bias
        float t0[8], t1[8];
        {
            const int rr[8] = {r01.x, r01.y, r01.z, r01.w, r2.x, r2.y, r2.z, r2.w};
            const int cc[8] = {c01.x, c01.y, c01.z, c01.w, c2.x, c2.y, c2.z, c2.w};
            #pragma unroll
            for (int e = 0; e < 8; e++) {
                float2 uu = *(const float2*)(u + (size_t)rr[e]*128 + 2*l);
                float2 vv = *(const float2*)(v + (size_t)cc[e]*128 + 2*l);
                t0[e] = b1a + uu.x + vv.x;
                t1[e] = b1b + uu.y + vv.y;
            }
        }

        // layer-1 GEMV: t += Wc^T * ise
        #pragma unroll 8
        for (int j2 = 0; j2 < 32; j2++) {
            float4 wq = w1pk[j2*64 + l];
            float4 xa = buf4[(2*j2)*2 + 0];
            float4 xbv = buf4[(2*j2)*2 + 1];
            float4 xc = buf4[(2*j2+1)*2 + 0];
            float4 xd = buf4[(2*j2+1)*2 + 1];
            t0[0] = fmaf(xa.x, wq.x, fmaf(xc.x, wq.z, t0[0]));
            t1[0] = fmaf(xa.x, wq.y, fmaf(xc.x, wq.w, t1[0]));
            t0[1] = fmaf(xa.y, wq.x, fmaf(xc.y, wq.z, t0[1]));
            t1[1] = fmaf(xa.y, wq.y, fmaf(xc.y, wq.w, t1[1]));
            t0[2] = fmaf(xa.z, wq.x, fmaf(xc.z, wq.z, t0[2]));
            t1[2] = fmaf(xa.z, wq.y, fmaf(xc.z, wq.w, t1[2]));
            t0[3] = fmaf(xa.w, wq.x, fmaf(xc.w, wq.z, t0[3]));
            t1[3] = fmaf(xa.w, wq.y, fmaf(xc.w, wq.w, t1[3]));
            t0[4] = fmaf(xbv.x, wq.x, fmaf(xd.x, wq.z, t0[4]));
            t1[4] = fmaf(xbv.x, wq.y, fmaf(xd.x, wq.w, t1[4]));
            t0[5] = fmaf(xbv.y, wq.x, fmaf(xd.y, wq.z, t0[5]));
            t1[5] = fmaf(xbv.y, wq.y, fmaf(xd.y, wq.w, t1[5]));
            t0[6] = fmaf(xbv.z, wq.x, fmaf(xd.z, wq.z, t0[6]));
            t1[6] = fmaf(xbv.z, wq.y, fmaf(xd.z, wq.w, t1[6]));
            t0[7] = fmaf(xbv.w, wq.x, fmaf(xd.w, wq.z, t0[7]));
            t1[7] = fmaf(xbv.w, wq.y, fmaf(xd.w, wq.w, t1[7]));
        }

        // h -> LDS (transposed per-edge rows), then layer 2
        #pragma unroll
        for (int e = 0; e < 8; e++) {
            *(float2*)(buf + e*128 + 2*l) = make_float2(relu_f(t0[e]), relu_f(t1[e]));
        }
        float o[8] = {0,0,0,0,0,0,0,0};
        #pragma unroll 8
        for (int k4 = 0; k4 < 32; k4++) {
            float4 wq = w2pk[k4*64 + l];
            #pragma unroll
            for (int e = 0; e < 8; e++) {
                float4 hb = *(const float4*)(buf + e*128 + 4*k4);
                o[e] = fmaf(hb.x, wq.x, fmaf(hb.y, wq.y,
                        fmaf(hb.z, wq.z, fmaf(hb.w, wq.w, o[e]))));
            }
        }
        {
            const int rr[8] = {r01.x, r01.y, r01.z, r01.w, r2.x, r2.y, r2.z, r2.w};
            const int cc[8] = {c01.x, c01.y, c01.z, c01.w, c2.x, c2.y, c2.z, c2.w};
            #pragma unroll
            for (int e = 0; e < 8; e++) {
                float ov = o[e] + b2r;
                atomicAdd(&hjp[(size_t)rr[e]*64 + l], ov);
                atomicAdd(&hjm[(size_t)cc[e]*64 + l], ov);
            }
        }
    }
}

// k_edge2f: per edge: tse = W1a*se; h1 = relu(tse + tp[col] + b1),
//           h2 = relu(tse + tm[row] + b1); o = W2*h + b2;
//           atomics: jac1[col]+=o1, jac2[row]+=o2
__global__ __launch_bounds__(256, 2) void k_edge2f(
    const int* __restrict__ ei, const float* __restrict__ ea,
    const float* __restrict__ tp, const float* __restrict__ tm,
    const float* __restrict__ eew, const float* __restrict__ eeb,
    const float* __restrict__ hW1, const float* __restrict__ hb1,
    const float* __restrict__ hW2, const float* __restrict__ hb2,
    float* __restrict__ jac1, float* __restrict__ jac2)
{
    extern __shared__ float lds[];
    float4* w1pk = (float4*)lds;                 // hW1 rows 0..63 pair-packed
    float4* w2pk = (float4*)(lds + 8192);        // hW2 quad-packed
    float*  bufbase = lds + 16384;

    for (int idx = threadIdx.x; idx < 32*64; idx += 256) {
        int j2 = idx >> 6, ll = idx & 63;
        float2 lo = ((const float2*)(hW1 + (2*j2)*128))[ll];
        float2 hi = ((const float2*)(hW1 + (2*j2 + 1)*128))[ll];
        w1pk[idx] = make_float4(lo.x, lo.y, hi.x, hi.y);
    }
    for (int idx = threadIdx.x; idx < 32*64; idx += 256) {
        int k4 = idx >> 6, ll = idx & 63;
        w2pk[idx] = make_float4(hW2[(4*k4+0)*64+ll], hW2[(4*k4+1)*64+ll],
                                hW2[(4*k4+2)*64+ll], hW2[(4*k4+3)*64+ll]);
    }
    __syncthreads();

    const int wid = threadIdx.x >> 6, l = threadIdx.x & 63;
    float* buf = bufbase + wid * 1024;
    float4* buf4 = (float4*)buf;

    const int jA = l >> 1;
    const int eh = l & 1;
    const float ewA0 = eew[jA],    ewB0 = eew[64+jA],  eb0v = eeb[jA];
    const float ewA1 = eew[jA+32], ewB1 = eew[96+jA],  eb1v = eeb[jA+32];
    const float b1a = hb1[2*l], b1b = hb1[2*l+1];
    const float b2r = hb2[l];

    const int gw = blockIdx.x * 4 + wid;
    const int nw = gridDim.x * 4;

    for (int g = gw; g < BE/8; g += nw) {
        const int e0 = g * 8;
        int4 r01 = *(const int4*)(ei + e0);
        int4 r2  = *(const int4*)(ei + e0 + 4);
        int4 c01 = *(const int4*)(ei + BE + e0);
        int4 c2  = *(const int4*)(ei + BE + e0 + 4);
        float4 sv0 = ((const float4*)(ea + 2*e0))[0];
        float4 sv1 = ((const float4*)(ea + 2*e0))[1];
        float4 sv2 = ((const float4*)(ea + 2*e0))[2];
        float4 sv3 = ((const float4*)(ea + 2*e0))[3];

        // se -> transposed xbuf
        {
            float4 svA = eh ? sv2 : sv0;
            float4 svB = eh ? sv3 : sv1;
            float4 p0, p1;
            p0.x = relu_f(fmaf(svA.x, ewA0, fmaf(svA.y, ewB0, eb0v)));
            p0.y = relu_f(fmaf(svA.z, ewA0, fmaf(svA.w, ewB0, eb0v)));
            p0.z = relu_f(fmaf(svB.x, ewA0, fmaf(svB.y, ewB0, eb0v)));
            p0.w = relu_f(fmaf(svB.z, ewA0, fmaf(svB.w, ewB0, eb0v)));
            p1.x = relu_f(fmaf(svA.x, ewA1, fmaf(svA.y, ewB1, eb1v)));
            p1.y = relu_f(fmaf(svA.z, ewA1, fmaf(svA.w, ewB1, eb1v)));
            p1.z = relu_f(fmaf(svB.x, ewA1, fmaf(svB.y, ewB1, eb1v)));
            p1.w = relu_f(fmaf(svB.z, ewA1, fmaf(svB.w, ewB1, eb1v)));
            buf4[jA*2 + eh]      = p0;
            buf4[(jA+32)*2 + eh] = p1;
        }

        const int rr[8] = {r01.x, r01.y, r01.z, r01.w, r2.x, r2.y, r2.z, r2.w};
        const int cc[8] = {c01.x, c01.y, c01.z, c01.w, c2.x, c2.y, c2.z, c2.w};

        // gather tp[col] while computing GEMV
        float2 tpv[8];
        #pragma unroll
        for (int e = 0; e < 8; e++)
            tpv[e] = *(const float2*)(tp + (size_t)cc[e]*128 + 2*l);

        float t0[8], t1[8];
        #pragma unroll
        for (int e = 0; e < 8; e++) { t0[e] = b1a; t1[e] = b1b; }

        #pragma unroll 8
        for (int j2 = 0; j2 < 32; j2++) {
            float4 wq = w1pk[j2*64 + l];
            float4 xa = buf4[(2*j2)*2 + 0];
            float4 xbv = buf4[(2*j2)*2 + 1];
            float4 xc = buf4[(2*j2+1)*2 + 0];
            float4 xd = buf4[(2*j2+1)*2 + 1];
            t0[0] = fmaf(xa.x, wq.x, fmaf(xc.x, wq.z, t0[0]));
            t1[0] = fmaf(xa.x, wq.y, fmaf(xc.x, wq.w, t1[0]));
            t0[1] = fmaf(xa.y, wq.x, fmaf(xc.y, wq.z, t0[1]));
            t1[1] = fmaf(xa.y, wq.y, fmaf(xc.y, wq.w, t1[1]));
            t0[2] = fmaf(xa.z, wq.x, fmaf(xc.z, wq.z, t0[2]));
            t1[2] = fmaf(xa.z, wq.y, fmaf(xc.z, wq.w, t1[2]));
            t0[3] = fmaf(xa.w, wq.x, fmaf(xc.w, wq.z, t0[3]));
            t1[3] = fmaf(xa.w, wq.y, fmaf(xc.w, wq.w, t1[3]));
            t0[4] = fmaf(xbv.x, wq.x, fmaf(xd.x, wq.z, t0[4]));
            t1[4] = fmaf(xbv.x, wq.y, fmaf(xd.x, wq.w, t1[4]));
            t0[5] = fmaf(xbv.y, wq.x, fmaf(xd.y, wq.z, t0[5]));
            t1[5] = fmaf(xbv.y, wq.y, fmaf(xd.y, wq.w, t1[5]));
            t0[6] = fmaf(xbv.z, wq.x, fmaf(xd.z, wq.z, t0[6]));
            t1[6] = fmaf(xbv.z, wq.y, fmaf(xd.z, wq.w, t1[6]));
            t0[7] = fmaf(xbv.w, wq.x, fmaf(xd.w, wq.z, t0[7]));
            t1[7] = fmaf(xbv.w, wq.y, fmaf(xd.w, wq.w, t1[7]));
        }

        // ---- pass A: h1 = relu(t + tp[col]) -> o1 -> jac1[col]
        #pragma unroll
        for (int e = 0; e < 8; e++) {
            *(float2*)(buf + e*128 + 2*l) =
                make_float2(relu_f(t0[e] + tpv[e].x), relu_f(t1[e] + tpv[e].y));
        }
        // prefetch tm[row] during pass A compute
        float2 tmv[8];
        #pragma unroll
        for (int e = 0; e < 8; e++)
            tmv[e] = *(const float2*)(tm + (size_t)rr[e]*128 + 2*l);

        float o1[8] = {0,0,0,0,0,0,0,0};
        #pragma unroll 8
        for (int k4 = 0; k4 < 32; k4++) {
            float4 wq = w2pk[k4*64 + l];
            #pragma unroll
            for (int e = 0; e < 8; e++) {
                float4 hb = *(const float4*)(buf + e*128 + 4*k4);
                o1[e] = fmaf(hb.x, wq.x, fmaf(hb.y, wq.y,
                         fmaf(hb.z, wq.z, fmaf(hb.w, wq.w, o1[e]))));
            }
        }
        #pragma unroll
        for (int e = 0; e < 8; e++)
            atomicAdd(&jac1[(size_t)cc[e]*64 + l], o1[e] + b2r);

        // ---- pass B: h2 = relu(t + tm[row]) -> o2 -> jac2[row]
        #pragma unroll
        for (int e = 0; e < 8; e++) {
            *(float2*)(buf + e*128 + 2*l) =
                make_float2(relu_f(t0[e] + tmv[e].x), relu_f(t1[e] + tmv[e].y));
        }
        float o2[8] = {0,0,0,0,0,0,0,0};
        #pragma unroll 8
        for (int k4 = 0; k4 < 32; k4++) {
            float4 wq = w2pk[k4*64 + l];
            #pragma unroll
            for (int e = 0; e < 8; e++) {
                float4 hb = *(const float4*)(buf + e*128 + 4*k4);
                o2[e] = fmaf(hb.x, wq.x, fmaf(hb.y, wq.y,
                         fmaf(hb.z, wq.z, fmaf(hb.w, wq.w, o2[e]))));
            }
        }
        #pragma unroll
        for (int e = 0; e < 8; e++)
            atomicAdd(&jac2[(size_t)rr[e]*64 + l], o2[e] + b2r);
    }
}

// ===========================================================================
// OLD-STYLE KERNELS (kept: node MLPs + final + fallback edge kernels)
// ===========================================================================
__global__ __launch_bounds__(256) void k_edge1(
    const int* __restrict__ ei, const float* __restrict__ ea,
    const float* __restrict__ node_emb,
    const float* __restrict__ e2w_g, const float* __restrict__ e2b_g,
    const float* __restrict__ dW1, const float* __restrict__ db1,
    const float* __restrict__ dW2, const float* __restrict__ db2,
    float* __restrict__ sumsp, float* __restrict__ hjp, float* __restrict__ hjm)
{
    extern __shared__ float lds[];
    float* w1 = lds;
    float* b1 = w1 + 192*128;
    float* w2 = b1 + 128;
    float* b2 = w2 + 128*64;
    float* ew = b2 + 64;
    float* eb = ew + 128;
    float* xreg = eb + 64;
    float* hreg = xreg + 4*768;

    for (int idx = threadIdx.x; idx < 192*128; idx += 256) w1[idx] = dW1[idx];
    for (int idx = threadIdx.x; idx < 128*64; idx += 256)  w2[idx] = dW2[idx];
    if (threadIdx.x < 128) { b1[threadIdx.x] = db1[threadIdx.x]; ew[threadIdx.x] = e2w_g[threadIdx.x]; }
    if (threadIdx.x < 64)  { b2[threadIdx.x] = db2[threadIdx.x]; eb[threadIdx.x] = e2b_g[threadIdx.x]; }
    __syncthreads();

    const int wid = threadIdx.x >> 6, l = threadIdx.x & 63;
    float* xbuf = xreg + wid * 768;
    float* hbuf = hreg + wid * 512;
    const int gw = blockIdx.x * 4 + wid;
    const int nw = gridDim.x * 4;

    for (int g = gw; g < BE/4; g += nw) {
        const int e0 = g * 4;
        int r[4], c[4];
        float s0[4], s1[4];
        #pragma unroll
        for (int e = 0; e < 4; e++) {
            r[e]  = ei[e0+e];
            c[e]  = ei[BE + e0+e];
            s0[e] = ea[(e0+e)*2+0];
            s1[e] = ea[(e0+e)*2+1];
        }
        if (l < 16) {
            int e = l >> 2, wch = l & 3;
            int node = (wch < 2) ? r[e] : c[e];
            float v = (wch & 1) ? s1[e] : s0[e];
            atomicAdd(&sumsp[node*2 + (wch & 1)], v);
        }
        float ar[4], cr[4], ir[4];
        #pragma unroll
        for (int e = 0; e < 4; e++) {
            ar[e] = node_emb[r[e]*64 + l];
            cr[e] = node_emb[c[e]*64 + l];
            float q0 = inv_clean(s0[e]), q1 = inv_clean(s1[e]);
            ir[e] = relu_f(fmaf(q0, ew[l], fmaf(q1, ew[64+l], eb[l])));
        }
        ((float4*)xbuf)[l]       = make_float4(ar[0], ar[1], ar[2], ar[3]);
        ((float4*)xbuf)[64 + l]  = make_float4(cr[0], cr[1], cr[2], cr[3]);
        ((float4*)xbuf)[128 + l] = make_float4(ir[0], ir[1], ir[2], ir[3]);

        float acc0[4] = {0,0,0,0}, acc1[4] = {0,0,0,0};
        #pragma unroll 8
        for (int j = 0; j < 192; j++) {
            float4 xv = ((const float4*)xbuf)[j];
            float2 wv = ((const float2*)(w1 + j*128))[l];
            acc0[0] = fmaf(xv.x, wv.x, acc0[0]);
            acc0[1] = fmaf(xv.y, wv.x, acc0[1]);
            acc0[2] = fmaf(xv.z, wv.x, acc0[2]);
            acc0[3] = fmaf(xv.w, wv.x, acc0[3]);
            acc1[0] = fmaf(xv.x, wv.y, acc1[0]);
            acc1[1] = fmaf(xv.y, wv.y, acc1[1]);
            acc1[2] = fmaf(xv.z, wv.y, acc1[2]);
            acc1[3] = fmaf(xv.w, wv.y, acc1[3]);
        }
        float bb0 = b1[2*l], bb1 = b1[2*l+1];
        #pragma unroll
        for (int e = 0; e < 4; e++) {
            float2 h = make_float2(relu_f(acc0[e]+bb0), relu_f(acc1[e]+bb1));
            ((float2*)(hbuf + e*128))[l] = h;
        }
        float o[4] = {0,0,0,0};
        #pragma unroll 8
        for (int k = 0; k < 128; k++) {
            float wv = w2[k*64 + l];
            o[0] = fmaf(hbuf[0*128+k], wv, o[0]);
            o[1] = fmaf(hbuf[1*128+k], wv, o[1]);
            o[2] = fmaf(hbuf[2*128+k], wv, o[2]);
            o[3] = fmaf(hbuf[3*128+k], wv, o[3]);
        }
        float bo = b2[l];
        #pragma unroll
        for (int e = 0; e < 4; e++) {
            float ov = o[e] + bo;
            atomicAdd(&hjp[r[e]*64 + l], ov);
            atomicAdd(&hjm[c[e]*64 + l], ov);
        }
    }
}

__global__ __launch_bounds__(256) void k_edge2(
    const int* __restrict__ ei, const float* __restrict__ ea,
    const float* __restrict__ hjp, const float* __restrict__ hjm,
    const float* __restrict__ eew_g, const float* __restrict__ eeb_g,
    const float* __restrict__ hW1, const float* __restrict__ hb1,
    const float* __restrict__ hW2, const float* __restrict__ hb2,
    float* __restrict__ jac1, float* __restrict__ jac2)
{
    extern __shared__ float lds[];
    float* w1 = lds;
    float* b1 = w1 + 128*128;
    float* w2 = b1 + 128;
    float* b2 = w2 + 128*64;
    float* ew = b2 + 64;
    float* eb = ew + 128;
    float* base = eb + 64;

    for (int idx = threadIdx.x; idx < 128*128; idx += 256) w1[idx] = hW1[idx];
    for (int idx = threadIdx.x; idx < 128*64; idx += 256)  w2[idx] = hW2[idx];
    if (threadIdx.x < 128) { b1[threadIdx.x] = hb1[threadIdx.x]; ew[threadIdx.x] = eew_g[threadIdx.x]; }
    if (threadIdx.x < 64)  { b2[threadIdx.x] = hb2[threadIdx.x]; eb[threadIdx.x] = eeb_g[threadIdx.x]; }
    __syncthreads();

    const int wid = threadIdx.x >> 6, l = threadIdx.x & 63;
    float* x1 = base + wid*2048;
    float* x2 = x1 + 512;
    float* h1 = x2 + 512;
    float* h2 = h1 + 512;
    const int gw = blockIdx.x * 4 + wid;
    const int nw = gridDim.x * 4;

    for (int g = gw; g < BE/4; g += nw) {
        const int e0 = g * 4;
        int r[4], c[4];
        float se[4], pa[4], pb[4];
        #pragma unroll
        for (int e = 0; e < 4; e++) {
            r[e] = ei[e0+e];
            c[e] = ei[BE + e0+e];
            float sp0 = ea[(e0+e)*2+0], sp1 = ea[(e0+e)*2+1];
            se[e] = relu_f(fmaf(sp0, ew[l], fmaf(sp1, ew[64+l], eb[l])));
            pa[e] = hjp[c[e]*64 + l];
            pb[e] = hjm[r[e]*64 + l];
        }
        ((float4*)x1)[l]      = make_float4(se[0], se[1], se[2], se[3]);
        ((float4*)x1)[64 + l] = make_float4(pa[0], pa[1], pa[2], pa[3]);
        ((float4*)x2)[l]      = make_float4(se[0], se[1], se[2], se[3]);
        ((float4*)x2)[64 + l] = make_float4(pb[0], pb[1], pb[2], pb[3]);

        float a0[4]={0,0,0,0}, a1[4]={0,0,0,0}, b0v[4]={0,0,0,0}, b1v[4]={0,0,0,0};
        #pragma unroll 8
        for (int j = 0; j < 128; j++) {
            float2 wv = ((const float2*)(w1 + j*128))[l];
            float4 xa = ((const float4*)x1)[j];
            float4 xb = ((const float4*)x2)[j];
            a0[0]=fmaf(xa.x,wv.x,a0[0]); a0[1]=fmaf(xa.y,wv.x,a0[1]);
            a0[2]=fmaf(xa.z,wv.x,a0[2]); a0[3]=fmaf(xa.w,wv.x,a0[3]);
            a1[0]=fmaf(xa.x,wv.y,a1[0]); a1[1]=fmaf(xa.y,wv.y,a1[1]);
            a1[2]=fmaf(xa.z,wv.y,a1[2]); a1[3]=fmaf(xa.w,wv.y,a1[3]);
            b0v[0]=fmaf(xb.x,wv.x,b0v[0]); b0v[1]=fmaf(xb.y,wv.x,b0v[1]);
            b0v[2]=fmaf(xb.z,wv.x,b0v[2]); b0v[3]=fmaf(xb.w,wv.x,b0v[3]);
            b1v[0]=fmaf(xb.x,wv.y,b1v[0]); b1v[1]=fmaf(xb.y,wv.y,b1v[1]);
            b1v[2]=fmaf(xb.z,wv.y,b1v[2]); b1v[3]=fmaf(xb.w,wv.y,b1v[3]);
        }
        float bb0 = b1[2*l], bb1 = b1[2*l+1];
        #pragma unroll
        for (int e = 0; e < 4; e++) {
            ((float2*)(h1 + e*128))[l] = make_float2(relu_f(a0[e]+bb0), relu_f(a1[e]+bb1));
            ((float2*)(h2 + e*128))[l] = make_float2(relu_f(b0v[e]+bb0), relu_f(b1v[e]+bb1));
        }
        float oA[4]={0,0,0,0}, oB[4]={0,0,0,0};
        #pragma unroll 8
        for (int k = 0; k < 128; k++) {
            float wv = w2[k*64 + l];
            oA[0]=fmaf(h1[0*128+k],wv,oA[0]); oA[1]=fmaf(h1[1*128+k],wv,oA[1]);
            oA[2]=fmaf(h1[2*128+k],wv,oA[2]); oA[3]=fmaf(h1[3*128+k],wv,oA[3]);
            oB[0]=fmaf(h2[0*128+k],wv,oB[0]); oB[1]=fmaf(h2[1*128+k],wv,oB[1]);
            oB[2]=fmaf(h2[2*128+k],wv,oB[2]); oB[3]=fmaf(h2[3*128+k],wv,oB[3]);
        }
        float bo = b2[l];
        #pragma unroll
        for (int e = 0; e < 4; e++) {
            atomicAdd(&jac1[c[e]*64 + l], oA[e] + bo);
            atomicAdd(&jac2[r[e]*64 + l], oB[e] + bo);
        }
    }
}

__global__ __launch_bounds__(256) void k_node_mlp(
    const float* __restrict__ A, const float* __restrict__ Bv,
    const float* __restrict__ sumsp,
    const float* __restrict__ e2w_g, const float* __restrict__ e2b_g,
    const float* __restrict__ W1g, const float* __restrict__ b1g,
    const float* __restrict__ W2g, const float* __restrict__ b2g,
    float* __restrict__ outp)
{
    extern __shared__ float lds[];
    float* w1 = lds;
    float* b1 = w1 + 192*128;
    float* w2 = b1 + 128;
    float* b2 = w2 + 128*64;
    float* ew = b2 + 64;
    float* eb = ew + 128;
    float* xreg = eb + 64;
    float* hreg = xreg + 4*768;

    for (int idx = threadIdx.x; idx < 192*128; idx += 256) w1[idx] = W1g[idx];
    for (int idx = threadIdx.x; idx < 128*64; idx += 256)  w2[idx] = W2g[idx];
    if (threadIdx.x < 128) { b1[threadIdx.x] = b1g[threadIdx.x]; ew[threadIdx.x] = e2w_g[threadIdx.x]; }
    if (threadIdx.x < 64)  { b2[threadIdx.x] = b2g[threadIdx.x]; eb[threadIdx.x] = e2b_g[threadIdx.x]; }
    __syncthreads();

    const int wid = threadIdx.x >> 6, l = threadIdx.x & 63;
    float* xbuf = xreg + wid * 768;
    float* hbuf = hreg + wid * 512;
    const int gw = blockIdx.x * 4 + wid;
    const int nw = gridDim.x * 4;

    for (int g = gw; g < BN/4; g += nw) {
        const int i0 = g * 4;
        float av[4], bv[4], iv[4];
        #pragma unroll
        for (int e = 0; e < 4; e++) {
            int i = i0 + e;
            av[e] = A[i*64 + l];
            bv[e] = Bv[i*64 + l];
            float q0 = inv_clean(sumsp[i*2+0]);
            float q1 = inv_clean(sumsp[i*2+1]);
            iv[e] = relu_f(fmaf(q0, ew[l], fmaf(q1, ew[64+l], eb[l])));
        }
        ((float4*)xbuf)[l]       = make_float4(av[0], av[1], av[2], av[3]);
        ((float4*)xbuf)[64 + l]  = make_float4(bv[0], bv[1], bv[2], bv[3]);
        ((float4*)xbuf)[128 + l] = make_float4(iv[0], iv[1], iv[2], iv[3]);

        float acc0[4] = {0,0,0,0}, acc1[4] = {0,0,0,0};
        #pragma unroll 8
        for (int j = 0; j < 192; j++) {
            float4 xv = ((const float4*)xbuf)[j];
            float2 wv = ((const float2*)(w1 + j*128))[l];
            acc0[0] = fmaf(xv.x, wv.x, acc0[0]);
            acc0[1] = fmaf(xv.y, wv.x, acc0[1]);
            acc0[2] = fmaf(xv.z, wv.x, acc0[2]);
            acc0[3] = fmaf(xv.w, wv.x, acc0[3]);
            acc1[0] = fmaf(xv.x, wv.y, acc1[0]);
            acc1[1] = fmaf(xv.y, wv.y, acc1[1]);
            acc1[2] = fmaf(xv.z, wv.y, acc1[2]);
            acc1[3] = fmaf(xv.w, wv.y, acc1[3]);
        }
        float bb0 = b1[2*l], bb1 = b1[2*l+1];
        #pragma unroll
        for (int e = 0; e < 4; e++) {
            ((float2*)(hbuf + e*128))[l] = make_float2(relu_f(acc0[e]+bb0), relu_f(acc1[e]+bb1));
        }
        float o[4] = {0,0,0,0};
        #pragma unroll 8
        for (int k = 0; k < 128; k++) {
            float wv = w2[k*64 + l];
            o[0] = fmaf(hbuf[0*128+k], wv, o[0]);
            o[1] = fmaf(hbuf[1*128+k], wv, o[1]);
            o[2] = fmaf(hbuf[2*128+k], wv, o[2]);
            o[3] = fmaf(hbuf[3*128+k], wv, o[3]);
        }
        float bo = b2[l];
        #pragma unroll
        for (int e = 0; e < 4; e++) outp[(i0+e)*64 + l] = o[e] + bo;
    }
}

__global__ __launch_bounds__(256) void k_node_final(
    const float* __restrict__ node_emb, const float* __restrict__ jacv,
    const float* __restrict__ hessv,
    const int* __restrict__ batch, const float* __restrict__ ga,
    const float* __restrict__ gw_g, const float* __restrict__ gb_g,
    const float* __restrict__ nW1, const float* __restrict__ nb1,
    const float* __restrict__ nW2, const float* __restrict__ nb2,
    const float* __restrict__ decW, const float* __restrict__ decb,
    const float* __restrict__ node_attr, float* __restrict__ outp)
{
    extern __shared__ float lds[];
    float* w1 = lds;
    float* b1 = w1 + 256*128;
    float* b2 = b1 + 128;
    float* gw = b2 + 64;
    float* gb = gw + 128;
    float* dw = gb + 64;
    float* db = dw + 128;
    float* xreg = db + 4;
    float* hreg = xreg + 4*1024;

    for (int idx = threadIdx.x; idx < 256*128; idx += 256) w1[idx] = nW1[idx];
    if (threadIdx.x < 128) { b1[threadIdx.x] = nb1[threadIdx.x]; gw[threadIdx.x] = gw_g[threadIdx.x]; dw[threadIdx.x] = decW[threadIdx.x]; }
    if (threadIdx.x < 64)  { b2[threadIdx.x] = nb2[threadIdx.x]; gb[threadIdx.x] = gb_g[threadIdx.x]; }
    if (threadIdx.x < 2)   { db[threadIdx.x] = decb[threadIdx.x]; }
    __syncthreads();

    const int wid = threadIdx.x >> 6, l = threadIdx.x & 63;
    float* xbuf = xreg + wid * 1024;
    float* hbuf = hreg + wid * 512;
    const int gwv = blockIdx.x * 4 + wid;
    const int nw = gridDim.x * 4;

    for (int g = gwv; g < BN/4; g += nw) {
        const int i0 = g * 4;
        float ne[4], jv[4], ge[4], hv[4];
        #pragma unroll
        for (int e = 0; e < 4; e++) {
            int i = i0 + e;
            ne[e] = node_emb[i*64 + l];
            jv[e] = jacv[i*64 + l];
            hv[e] = hessv[i*64 + l];
            int gi = batch[i];
            ge[e] = relu_f(fmaf(ga[gi*2], gw[l], fmaf(ga[gi*2+1], gw[64+l], gb[l])));
        }
        ((float4*)xbuf)[l]       = make_float4(ne[0], ne[1], ne[2], ne[3]);
        ((float4*)xbuf)[64 + l]  = make_float4(jv[0], jv[1], jv[2], jv[3]);
        ((float4*)xbuf)[128 + l] = make_float4(ge[0], ge[1], ge[2], ge[3]);
        ((float4*)xbuf)[192 + l] = make_float4(hv[0], hv[1], hv[2], hv[3]);

        float acc0[4] = {0,0,0,0}, acc1[4] = {0,0,0,0};
        #pragma unroll 8
        for (int j = 0; j < 256; j++) {
            float4 xv = ((const float4*)xbuf)[j];
            float2 wv = ((const float2*)(w1 + j*128))[l];
            acc0[0] = fmaf(xv.x, wv.x, acc0[0]);
            acc0[1] = fmaf(xv.y, wv.x, acc0[1]);
            acc0[2] = fmaf(xv.z, wv.x, acc0[2]);
            acc0[3] = fmaf(xv.w, wv.x, acc0[3]);
            acc1[0] = fmaf(xv.x, wv.y, acc1[0]);
            acc1[1] = fmaf(xv.y, wv.y, acc1[1]);
            acc1[2] = fmaf(xv.z, wv.y, acc1[2]);
            acc1[3] = fmaf(xv.w, wv.y, acc1[3]);
        }
        float bb0 = b1[2*l], bb1 = b1[2*l+1];
        #pragma unroll
        for (int e = 0; e < 4; e++) {
            ((float2*)(hbuf + e*128))[l] = make_float2(relu_f(acc0[e]+bb0), relu_f(acc1[e]+bb1));
        }
        float o[4] = {0,0,0,0};
        #pragma unroll 8
        for (int k = 0; k < 128; k++) {
            float wv = nW2[k*64 + l];
            o[0] = fmaf(hbuf[0*128+k], wv, o[0]);
            o[1] = fmaf(hbuf[1*128+k], wv, o[1]);
            o[2] = fmaf(hbuf[2*128+k], wv, o[2]);
            o[3] = fmaf(hbuf[3*128+k], wv, o[3]);
        }
        float bo = b2[l];
        #pragma unroll
        for (int e = 0; e < 4; e++) hbuf[e*128 + l] = o[e] + bo;

        int e2 = l >> 4, sub = l & 15, j2 = sub >> 3, part = sub & 7;
        float s = 0.0f;
        #pragma unroll
        for (int kk = 0; kk < 8; kk++) {
            int k = part*8 + kk;
            s = fmaf(hbuf[e2*128 + k], dw[k*2 + j2], s);
        }
        s += __shfl_xor(s, 1);
        s += __shfl_xor(s, 2);
        s += __shfl_xor(s, 4);
        if (part == 0) {
            int i = i0 + e2;
            outp[i*2 + j2] = (s + db[j2]) * node_attr[i*2 + j2];
        }
    }
}

// ===========================================================================
extern "C" void kernel_launch(void* const* d_in, const int* in_sizes, int n_in,
                              void* d_out, int out_size, void* d_ws, size_t ws_size,
                              hipStream_t stream) {
    const float* x          = (const float*)d_in[0];
    const int*   ei         = (const int*)  d_in[1];
    const int*   batch      = (const int*)  d_in[2];
    const float* node_attr  = (const float*)d_in[3];
    const float* edge_attr  = (const float*)d_in[4];
    const float* glob_attr  = (const float*)d_in[5];
    const float* enc_node_W = (const float*)d_in[6];
    const float* enc_node_b = (const float*)d_in[7];
    const float* enc_edge_W = (const float*)d_in[8];
    const float* enc_edge_b = (const float*)d_in[9];
    const float* enc_glob_W = (const float*)d_in[10];
    const float* enc_glob_b = (const float*)d_in[11];
    const float* enc2_W     = (const float*)d_in[12];
    const float* enc2_b     = (const float*)d_in[13];
    const float* dW1 = (const float*)d_in[14]; const float* db1 = (const float*)d_in[15];
    const float* dW2 = (const float*)d_in[16]; const float* db2 = (const float*)d_in[17];
    const float* hW1 = (const float*)d_in[18]; const float* hb1 = (const float*)d_in[19];
    const float* hW2 = (const float*)d_in[20]; const float* hb2 = (const float*)d_in[21];
    const float* jW1 = (const float*)d_in[22]; const float* jb1 = (const float*)d_in[23];
    const float* jW2 = (const float*)d_in[24]; const float* jb2 = (const float*)d_in[25];
    const float* sW1 = (const float*)d_in[26]; const float* sb1 = (const float*)d_in[27];
    const float* sW2 = (const float*)d_in[28]; const float* sb2 = (const float*)d_in[29];
    const float* nW1 = (const float*)d_in[30]; const float* nb1 = (const float*)d_in[31];
    const float* nW2 = (const float*)d_in[32]; const float* nb2 = (const float*)d_in[33];
    const float* decW = (const float*)d_in[34]; const float* decb = (const float*)d_in[35];

    float* ws = (float*)d_ws;
    const size_t NEED_FAST = 28900000ull * sizeof(float);   // 115.6 MB

    if (ws_size >= NEED_FAST) {
        // -------- fast path: linear-split pipeline --------
        float* ne    = ws;                      // 3.2M
        float* u     = ne + 3200000;            // 6.4M  (later tp)
        float* v     = u + 6400000;             // 6.4M  (later tm)
        float* hjp   = v + 6400000;             // 3.2M  (later hess)
        float* hjm   = hjp + 3200000;           // 3.2M
        float* jac1  = hjm + 3200000;           // 3.2M  (later jac)
        float* jac2  = jac1 + 3200000;          // 3.2M
        float* sumsp = jac2 + 3200000;          // 100K

        hipMemsetAsync(hjp, 0, (size_t)4*3200000*sizeof(float), stream);
        hipMemsetAsync(sumsp, 0, (size_t)100000*sizeof(float), stream);

        k_node_enc<<<12500, 256, 0, stream>>>(x, enc_node_W, enc_node_b, ne);

        size_t lds_uv = 18432u * sizeof(float);     // 72 KB
        k_uv<<<512, 256, lds_uv, stream>>>(ne, dW1, u, v);

        size_t lds_e = 20480u * sizeof(float);      // 80 KB
        k_edge1f<<<512, 256, lds_e, stream>>>(ei, edge_attr, u, v, enc2_W, enc2_b,
                                              dW1, db1, dW2, db2, sumsp, hjp, hjm);

        size_t lds_tptm = 10240u * sizeof(float);   // 40 KB
        k_tptm<<<512, 256, lds_tptm, stream>>>(hjp, hjm, hW1, u, v);  // tp->u, tm->v

        k_edge2f<<<512, 256, lds_e, stream>>>(ei, edge_attr, u, v,
                                              enc_edge_W, enc_edge_b,
                                              hW1, hb1, hW2, hb2, jac1, jac2);

        size_t lds3 = 38272u * sizeof(float);
        k_node_mlp<<<256, 256, lds3, stream>>>(jac1, jac2, sumsp, enc2_W, enc2_b,
                                               jW1, jb1, jW2, jb2, jac1);
        k_node_mlp<<<256, 256, lds3, stream>>>(hjp, hjm, sumsp, enc2_W, enc2_b,
                                               sW1, sb1, sW2, sb2, hjp);

        size_t lds4 = 39428u * sizeof(float);
        k_node_final<<<256, 256, lds4, stream>>>(ne, jac1, hjp,
                                                 batch, glob_attr, enc_glob_W, enc_glob_b,
                                                 nW1, nb1, nW2, nb2, decW, decb,
                                                 node_attr, (float*)d_out);
    } else {
        // -------- fallback: round-1 pipeline (64.4 MB) --------
        float* node_emb = ws;
        float* hjp   = node_emb + 3200000;
        float* hjm   = hjp + 3200000;
        float* jac1  = hjm + 3200000;
        float* jac2  = jac1 + 3200000;
        float* sumsp = jac2 + 3200000;

        hipMemsetAsync(hjp, 0, (size_t)4*3200000*sizeof(float), stream);
        hipMemsetAsync(sumsp, 0, (size_t)100000*sizeof(float), stream);

        k_node_enc<<<12500, 256, 0, stream>>>(x, enc_node_W, enc_node_b, node_emb);

        size_t lds1 = 38272u * sizeof(float);
        k_edge1<<<256, 256, lds1, stream>>>(ei, edge_attr, node_emb, enc2_W, enc2_b,
                                            dW1, db1, dW2, db2, sumsp, hjp, hjm);

        size_t lds2 = 33152u * sizeof(float);
        k_edge2<<<256, 256, lds2, stream>>>(ei, edge_attr, hjp, hjm,
                                            enc_edge_W, enc_edge_b,
                                            hW1, hb1, hW2, hb2, jac1, jac2);

        size_t lds3 = 38272u * sizeof(float);
        k_node_mlp<<<256, 256, lds3, stream>>>(jac1, jac2, sumsp, enc2_W, enc2_b,
                                               jW1, jb1, jW2, jb2, jac1);
        k_node_mlp<<<256, 256, lds3, stream>>>(hjp, hjm, sumsp, enc2_W, enc2_b,
                                               sW1, sb1, sW2, sb2, hjp);

        size_t lds4 = 39428u * sizeof(float);
        k_node_final<<<256, 256, lds4, stream>>>(node_emb, jac1, hjp,
                                                 batch, glob_attr, enc_glob_W, enc_glob_b,
                                                 nW1, nb1, nW2, nb2, decW, decb,
                                                 node_attr, (float*)d_out);
    }
}

// Round 3
// 2091.917 us; speedup vs baseline: 2.6969x; 1.0225x over previous
//
#include <hip/hip_runtime.h>
#include <math.h>

#define BN 50000
#define BE 800000

__device__ __forceinline__ float relu_f(float v) { return fmaxf(v, 0.0f); }
__device__ __forceinline__ float inv_clean(float s) {
    float q = 1.0f / s;
    return isfinite(q) ? q : 0.0f;
}
__device__ __forceinline__ float inv_clean_fast(float s) {
    float q = __builtin_amdgcn_rcpf(s);
    return isfinite(q) ? q : 0.0f;
}

// ===========================================================================
// Weight packing kernels (run once per call; outputs live in d_out scratch,
// which k_node_final fully overwrites at the end).
// ===========================================================================
// pair-pack rows r0..r0+63 of a [*,128] W1 into [32 j2][64 l] float4
__global__ __launch_bounds__(256) void k_pack_w1(
    const float* __restrict__ W, int r0, float4* __restrict__ dst)
{
    int t = blockIdx.x * 256 + threadIdx.x;    // 2048 total
    if (t >= 2048) return;
    int j2 = t >> 6, l = t & 63;
    const float* ra = W + (size_t)(r0 + 2*j2) * 128 + 2*l;
    const float* rb = W + (size_t)(r0 + 2*j2 + 1) * 128 + 2*l;
    dst[t] = make_float4(ra[0], ra[1], rb[0], rb[1]);
}
// quad-pack a [128,64] W2 into [32 k4][64 l] float4
__global__ __launch_bounds__(256) void k_pack_w2(
    const float* __restrict__ W2, float4* __restrict__ dst)
{
    int t = blockIdx.x * 256 + threadIdx.x;    // 2048 total
    if (t >= 2048) return;
    int k4 = t >> 6, l = t & 63;
    dst[t] = make_float4(W2[(4*k4+0)*64+l], W2[(4*k4+1)*64+l],
                         W2[(4*k4+2)*64+l], W2[(4*k4+3)*64+l]);
}
// pack dW1 (rows 0..127) for k_uv: [64 j][64 l] float4
__global__ __launch_bounds__(256) void k_pack_uv(
    const float* __restrict__ dW1, float4* __restrict__ dst)
{
    int t = blockIdx.x * 256 + threadIdx.x;    // 4096 total
    if (t >= 4096) return;
    int j = t >> 6, l = t & 63;
    float4 w;
    if (l < 32) w = ((const float4*)(dW1 + (size_t)j*128))[l];
    else        w = ((const float4*)(dW1 + (size_t)(64+j)*128))[l-32];
    dst[t] = w;
}

// ===========================================================================
// Kernel 1: node encoder  node_emb = relu(x @ W + b)   [BN,2]@[2,64]
// ===========================================================================
__global__ __launch_bounds__(256) void k_node_enc(
    const float* __restrict__ x, const float* __restrict__ W,
    const float* __restrict__ b, float* __restrict__ node_emb)
{
    int t = blockIdx.x * 256 + threadIdx.x;
    int i = t >> 6, l = t & 63;
    float v = fmaf(x[i*2], W[l], fmaf(x[i*2+1], W[64+l], b[l]));
    node_emb[t] = relu_f(v);
}

// ===========================================================================
// FAST PATH KERNELS — weights read from packed GLOBAL arrays (L1/L2-hot),
// LDS holds only per-wave staging buffers -> high occupancy.
// ===========================================================================

// k_uv: u[n] = ne[n] @ dW1[0:64,:],  v[n] = ne[n] @ dW1[64:128,:]
__global__ __launch_bounds__(256, 6) void k_uv(
    const float* __restrict__ ne, const float4* __restrict__ guv,
    float* __restrict__ u, float* __restrict__ v)
{
    extern __shared__ float lds[];                  // 4 waves * 512 f
    const int wid = threadIdx.x >> 6, l = threadIdx.x & 63;
    float4* xb4 = (float4*)(lds + wid * 512);
    const int gw = blockIdx.x * 4 + wid;
    const int nw = gridDim.x * 4;

    for (int g = gw; g < BN/8; g += nw) {
        const int n0 = g * 8;
        const int q = l >> 5;
        #pragma unroll
        for (int r = 0; r < 2; r++) {
            int j = (l & 31) + 32*r;
            float v0 = ne[(n0 + q*4 + 0)*64 + j];
            float v1 = ne[(n0 + q*4 + 1)*64 + j];
            float v2 = ne[(n0 + q*4 + 2)*64 + j];
            float v3 = ne[(n0 + q*4 + 3)*64 + j];
            xb4[j*2 + q] = make_float4(v0, v1, v2, v3);
        }
        float4 acc[8];
        #pragma unroll
        for (int e = 0; e < 8; e++) acc[e] = make_float4(0,0,0,0);
        #pragma unroll 8
        for (int j = 0; j < 64; j++) {
            float4 wq = guv[j*64 + l];
            float4 xa = xb4[j*2 + 0];
            float4 xc = xb4[j*2 + 1];
            acc[0].x = fmaf(xa.x, wq.x, acc[0].x); acc[0].y = fmaf(xa.x, wq.y, acc[0].y);
            acc[0].z = fmaf(xa.x, wq.z, acc[0].z); acc[0].w = fmaf(xa.x, wq.w, acc[0].w);
            acc[1].x = fmaf(xa.y, wq.x, acc[1].x); acc[1].y = fmaf(xa.y, wq.y, acc[1].y);
            acc[1].z = fmaf(xa.y, wq.z, acc[1].z); acc[1].w = fmaf(xa.y, wq.w, acc[1].w);
            acc[2].x = fmaf(xa.z, wq.x, acc[2].x); acc[2].y = fmaf(xa.z, wq.y, acc[2].y);
            acc[2].z = fmaf(xa.z, wq.z, acc[2].z); acc[2].w = fmaf(xa.z, wq.w, acc[2].w);
            acc[3].x = fmaf(xa.w, wq.x, acc[3].x); acc[3].y = fmaf(xa.w, wq.y, acc[3].y);
            acc[3].z = fmaf(xa.w, wq.z, acc[3].z); acc[3].w = fmaf(xa.w, wq.w, acc[3].w);
            acc[4].x = fmaf(xc.x, wq.x, acc[4].x); acc[4].y = fmaf(xc.x, wq.y, acc[4].y);
            acc[4].z = fmaf(xc.x, wq.z, acc[4].z); acc[4].w = fmaf(xc.x, wq.w, acc[4].w);
            acc[5].x = fmaf(xc.y, wq.x, acc[5].x); acc[5].y = fmaf(xc.y, wq.y, acc[5].y);
            acc[5].z = fmaf(xc.y, wq.z, acc[5].z); acc[5].w = fmaf(xc.y, wq.w, acc[5].w);
            acc[6].x = fmaf(xc.z, wq.x, acc[6].x); acc[6].y = fmaf(xc.z, wq.y, acc[6].y);
            acc[6].z = fmaf(xc.z, wq.z, acc[6].z); acc[6].w = fmaf(xc.z, wq.w, acc[6].w);
            acc[7].x = fmaf(xc.w, wq.x, acc[7].x); acc[7].y = fmaf(xc.w, wq.y, acc[7].y);
            acc[7].z = fmaf(xc.w, wq.z, acc[7].z); acc[7].w = fmaf(xc.w, wq.w, acc[7].w);
        }
        float* dst = (l < 32) ? (u + 4*l) : (v + 4*(l-32));
        #pragma unroll
        for (int e = 0; e < 8; e++) {
            *(float4*)(dst + (size_t)(n0+e)*128) = acc[e];
        }
    }
}

// k_tptm: tp[n] = hjp[n] @ hW1[64:128,:], tm[n] = hjm[n] @ hW1[64:128,:]
__global__ __launch_bounds__(256, 6) void k_tptm(
    const float* __restrict__ hjp, const float* __restrict__ hjm,
    const float4* __restrict__ gtp,
    float* __restrict__ tp, float* __restrict__ tm)
{
    extern __shared__ float lds[];                  // 4 waves * 512 f
    const int wid = threadIdx.x >> 6, l = threadIdx.x & 63;
    float4* xb4 = (float4*)(lds + wid * 512);
    const int gw = blockIdx.x * 4 + wid;
    const int nw = gridDim.x * 4;
    const int NG = BN/8;

    for (int vg = gw; vg < 2*NG; vg += nw) {
        const float* in  = (vg < NG) ? hjp : hjm;
        float*       out = (vg < NG) ? tp  : tm;
        const int n0 = ((vg < NG) ? vg : vg - NG) * 8;
        const int q = l >> 5;
        #pragma unroll
        for (int r = 0; r < 2; r++) {
            int j = (l & 31) + 32*r;
            float v0 = in[(n0 + q*4 + 0)*64 + j];
            float v1 = in[(n0 + q*4 + 1)*64 + j];
            float v2 = in[(n0 + q*4 + 2)*64 + j];
            float v3 = in[(n0 + q*4 + 3)*64 + j];
            xb4[j*2 + q] = make_float4(v0, v1, v2, v3);
        }
        float a0[8] = {0,0,0,0,0,0,0,0}, a1[8] = {0,0,0,0,0,0,0,0};
        #pragma unroll 8
        for (int j2 = 0; j2 < 32; j2++) {
            float4 wq = gtp[j2*64 + l];
            float4 xa = xb4[(2*j2)*2 + 0];
            float4 xbv = xb4[(2*j2)*2 + 1];
            float4 xc = xb4[(2*j2+1)*2 + 0];
            float4 xd = xb4[(2*j2+1)*2 + 1];
            a0[0] = fmaf(xa.x, wq.x, fmaf(xc.x, wq.z, a0[0]));
            a1[0] = fmaf(xa.x, wq.y, fmaf(xc.x, wq.w, a1[0]));
            a0[1] = fmaf(xa.y, wq.x, fmaf(xc.y, wq.z, a0[1]));
            a1[1] = fmaf(xa.y, wq.y, fmaf(xc.y, wq.w, a1[1]));
            a0[2] = fmaf(xa.z, wq.x, fmaf(xc.z, wq.z, a0[2]));
            a1[2] = fmaf(xa.z, wq.y, fmaf(xc.z, wq.w, a1[2]));
            a0[3] = fmaf(xa.w, wq.x, fmaf(xc.w, wq.z, a0[3]));
            a1[3] = fmaf(xa.w, wq.y, fmaf(xc.w, wq.w, a1[3]));
            a0[4] = fmaf(xbv.x, wq.x, fmaf(xd.x, wq.z, a0[4]));
            a1[4] = fmaf(xbv.x, wq.y, fmaf(xd.x, wq.w, a1[4]));
            a0[5] = fmaf(xbv.y, wq.x, fmaf(xd.y, wq.z, a0[5]));
            a1[5] = fmaf(xbv.y, wq.y, fmaf(xd.y, wq.w, a1[5]));
            a0[6] = fmaf(xbv.z, wq.x, fmaf(xd.z, wq.z, a0[6]));
            a1[6] = fmaf(xbv.z, wq.y, fmaf(xd.z, wq.w, a1[6]));
            a0[7] = fmaf(xbv.w, wq.x, fmaf(xd.w, wq.z, a0[7]));
            a1[7] = fmaf(xbv.w, wq.y, fmaf(xd.w, wq.w, a1[7]));
        }
        #pragma unroll
        for (int e = 0; e < 8; e++) {
            *(float2*)(out + (size_t)(n0+e)*128 + 2*l) = make_float2(a0[e], a1[e]);
        }
    }
}

// k_edge1f: t = u[row] + v[col] + Wc*ise + b1; h=relu(t); o=W2*h+b2
__global__ __launch_bounds__(256, 6) void k_edge1f(
    const int* __restrict__ ei, const float* __restrict__ ea,
    const float* __restrict__ u, const float* __restrict__ v,
    const float* __restrict__ e2w, const float* __restrict__ e2b,
    const float4* __restrict__ gw1, const float* __restrict__ db1,
    const float4* __restrict__ gw2, const float* __restrict__ db2,
    float* __restrict__ sumsp, float* __restrict__ hjp, float* __restrict__ hjm)
{
    extern __shared__ float lds[];                   // 4 waves * 1024 f
    const int wid = threadIdx.x >> 6, l = threadIdx.x & 63;
    float* buf = lds + wid * 1024;
    float4* buf4 = (float4*)buf;

    const int jA = l >> 1;
    const int eh = l & 1;
    const float ewA0 = e2w[jA],      ewB0 = e2w[64+jA],    eb0v = e2b[jA];
    const float ewA1 = e2w[jA+32],   ewB1 = e2w[96+jA],    eb1v = e2b[jA+32];
    const float b1a = db1[2*l], b1b = db1[2*l+1];
    const float b2r = db2[l];

    const int gw = blockIdx.x * 4 + wid;
    const int nw = gridDim.x * 4;

    for (int g = gw; g < BE/8; g += nw) {
        const int e0 = g * 8;
        int4 r01 = *(const int4*)(ei + e0);
        int4 r2  = *(const int4*)(ei + e0 + 4);
        int4 c01 = *(const int4*)(ei + BE + e0);
        int4 c2  = *(const int4*)(ei + BE + e0 + 4);
        float4 sv0 = ((const float4*)(ea + 2*e0))[0];
        float4 sv1 = ((const float4*)(ea + 2*e0))[1];
        float4 sv2 = ((const float4*)(ea + 2*e0))[2];
        float4 sv3 = ((const float4*)(ea + 2*e0))[3];

        if (l < 32) {
            int e = l >> 2, wch = l & 3;
            int4 rA = (e & 4) ? r2 : r01;
            int rx = (e & 2) ? ((e & 1) ? rA.w : rA.z) : ((e & 1) ? rA.y : rA.x);
            int4 cA = (e & 4) ? c2 : c01;
            int cx = (e & 2) ? ((e & 1) ? cA.w : cA.z) : ((e & 1) ? cA.y : cA.x);
            float4 sA = (e & 4) ? ((e & 2) ? sv3 : sv2) : ((e & 2) ? sv1 : sv0);
            float s0e = (e & 1) ? sA.z : sA.x;
            float s1e = (e & 1) ? sA.w : sA.y;
            int node = (wch < 2) ? rx : cx;
            int comp = wch & 1;
            float val = comp ? s1e : s0e;
            atomicAdd(&sumsp[node*2 + comp], val);
        }

        {
            float4 svA = eh ? sv2 : sv0;
            float4 svB = eh ? sv3 : sv1;
            float q00 = inv_clean_fast(svA.x), q10 = inv_clean_fast(svA.y);
            float q01 = inv_clean_fast(svA.z), q11 = inv_clean_fast(svA.w);
            float q02 = inv_clean_fast(svB.x), q12 = inv_clean_fast(svB.y);
            float q03 = inv_clean_fast(svB.z), q13 = inv_clean_fast(svB.w);
            float4 p0, p1;
            p0.x = relu_f(fmaf(q00, ewA0, fmaf(q10, ewB0, eb0v)));
            p0.y = relu_f(fmaf(q01, ewA0, fmaf(q11, ewB0, eb0v)));
            p0.z = relu_f(fmaf(q02, ewA0, fmaf(q12, ewB0, eb0v)));
            p0.w = relu_f(fmaf(q03, ewA0, fmaf(q13, ewB0, eb0v)));
            p1.x = relu_f(fmaf(q00, ewA1, fmaf(q10, ewB1, eb1v)));
            p1.y = relu_f(fmaf(q01, ewA1, fmaf(q11, ewB1, eb1v)));
            p1.z = relu_f(fmaf(q02, ewA1, fmaf(q12, ewB1, eb1v)));
            p1.w = relu_f(fmaf(q03, ewA1, fmaf(q13, ewB1, eb1v)));
            buf4[jA*2 + eh]      = p0;
            buf4[(jA+32)*2 + eh] = p1;
        }

        float t0[8], t1[8];
        {
            const int rr[8] = {r01.x, r01.y, r01.z, r01.w, r2.x, r2.y, r2.z, r2.w};
            const int cc[8] = {c01.x, c01.y, c01.z, c01.w, c2.x, c2.y, c2.z, c2.w};
            #pragma unroll
            for (int e = 0; e < 8; e++) {
                float2 uu = *(const float2*)(u + (size_t)rr[e]*128 + 2*l);
                float2 vv = *(const float2*)(v + (size_t)cc[e]*128 + 2*l);
                t0[e] = b1a + uu.x + vv.x;
                t1[e] = b1b + uu.y + vv.y;
            }
        }

        #pragma unroll 8
        for (int j2 = 0; j2 < 32; j2++) {
            float4 wq = gw1[j2*64 + l];
            float4 xa = buf4[(2*j2)*2 + 0];
            float4 xbv = buf4[(2*j2)*2 + 1];
            float4 xc = buf4[(2*j2+1)*2 + 0];
            float4 xd = buf4[(2*j2+1)*2 + 1];
            t0[0] = fmaf(xa.x, wq.x, fmaf(xc.x, wq.z, t0[0]));
            t1[0] = fmaf(xa.x, wq.y, fmaf(xc.x, wq.w, t1[0]));
            t0[1] = fmaf(xa.y, wq.x, fmaf(xc.y, wq.z, t0[1]));
            t1[1] = fmaf(xa.y, wq.y, fmaf(xc.y, wq.w, t1[1]));
            t0[2] = fmaf(xa.z, wq.x, fmaf(xc.z, wq.z, t0[2]));
            t1[2] = fmaf(xa.z, wq.y, fmaf(xc.z, wq.w, t1[2]));
            t0[3] = fmaf(xa.w, wq.x, fmaf(xc.w, wq.z, t0[3]));
            t1[3] = fmaf(xa.w, wq.y, fmaf(xc.w, wq.w, t1[3]));
            t0[4] = fmaf(xbv.x, wq.x, fmaf(xd.x, wq.z, t0[4]));
            t1[4] = fmaf(xbv.x, wq.y, fmaf(xd.x, wq.w, t1[4]));
            t0[5] = fmaf(xbv.y, wq.x, fmaf(xd.y, wq.z, t0[5]));
            t1[5] = fmaf(xbv.y, wq.y, fmaf(xd.y, wq.w, t1[5]));
            t0[6] = fmaf(xbv.z, wq.x, fmaf(xd.z, wq.z, t0[6]));
            t1[6] = fmaf(xbv.z, wq.y, fmaf(xd.z, wq.w, t1[6]));
            t0[7] = fmaf(xbv.w, wq.x, fmaf(xd.w, wq.z, t0[7]));
            t1[7] = fmaf(xbv.w, wq.y, fmaf(xd.w, wq.w, t1[7]));
        }

        #pragma unroll
        for (int e = 0; e < 8; e++) {
            *(float2*)(buf + e*128 + 2*l) = make_float2(relu_f(t0[e]), relu_f(t1[e]));
        }
        float o[8] = {0,0,0,0,0,0,0,0};
        #pragma unroll 8
        for (int k4 = 0; k4 < 32; k4++) {
            float4 wq = gw2[k4*64 + l];
            #pragma unroll
            for (int e = 0; e < 8; e++) {
                float4 hb = *(const float4*)(buf + e*128 + 4*k4);
                o[e] = fmaf(hb.x, wq.x, fmaf(hb.y, wq.y,
                        fmaf(hb.z, wq.z, fmaf(hb.w, wq.w, o[e]))));
            }
        }
        {
            const int rr[8] = {r01.x, r01.y, r01.z, r01.w, r2.x, r2.y, r2.z, r2.w};
            const int cc[8] = {c01.x, c01.y, c01.z, c01.w, c2.x, c2.y, c2.z, c2.w};
            #pragma unroll
            for (int e = 0; e < 8; e++) {
                float ov = o[e] + b2r;
                atomicAdd(&hjp[(size_t)rr[e]*64 + l], ov);
                atomicAdd(&hjm[(size_t)cc[e]*64 + l], ov);
            }
        }
    }
}

// k_edge2f: tse = W1a*se; h1 = relu(tse + tp[col] + b1), h2 = relu(tse + tm[row] + b1)
__global__ __launch_bounds__(256, 6) void k_edge2f(
    const int* __restrict__ ei, const float* __restrict__ ea,
    const float* __restrict__ tp, const float* __restrict__ tm,
    const float* __restrict__ eew, const float* __restrict__ eeb,
    const float4* __restrict__ gw1, const float* __restrict__ hb1,
    const float4* __restrict__ gw2, const float* __restrict__ hb2,
    float* __restrict__ jac1, float* __restrict__ jac2)
{
    extern __shared__ float lds[];                   // 4 waves * 1024 f
    const int wid = threadIdx.x >> 6, l = threadIdx.x & 63;
    float* buf = lds + wid * 1024;
    float4* buf4 = (float4*)buf;

    const int jA = l >> 1;
    const int eh = l & 1;
    const float ewA0 = eew[jA],    ewB0 = eew[64+jA],  eb0v = eeb[jA];
    const float ewA1 = eew[jA+32], ewB1 = eew[96+jA],  eb1v = eeb[jA+32];
    const float b1a = hb1[2*l], b1b = hb1[2*l+1];
    const float b2r = hb2[l];

    const int gw = blockIdx.x * 4 + wid;
    const int nw = gridDim.x * 4;

    for (int g = gw; g < BE/8; g += nw) {
        const int e0 = g * 8;
        int4 r01 = *(const int4*)(ei + e0);
        int4 r2  = *(const int4*)(ei + e0 + 4);
        int4 c01 = *(const int4*)(ei + BE + e0);
        int4 c2  = *(const int4*)(ei + BE + e0 + 4);
        float4 sv0 = ((const float4*)(ea + 2*e0))[0];
        float4 sv1 = ((const float4*)(ea + 2*e0))[1];
        float4 sv2 = ((const float4*)(ea + 2*e0))[2];
        float4 sv3 = ((const float4*)(ea + 2*e0))[3];

        {
            float4 svA = eh ? sv2 : sv0;
            float4 svB = eh ? sv3 : sv1;
            float4 p0, p1;
            p0.x = relu_f(fmaf(svA.x, ewA0, fmaf(svA.y, ewB0, eb0v)));
            p0.y = relu_f(fmaf(svA.z, ewA0, fmaf(svA.w, ewB0, eb0v)));
            p0.z = relu_f(fmaf(svB.x, ewA0, fmaf(svB.y, ewB0, eb0v)));
            p0.w = relu_f(fmaf(svB.z, ewA0, fmaf(svB.w, ewB0, eb0v)));
            p1.x = relu_f(fmaf(svA.x, ewA1, fmaf(svA.y, ewB1, eb1v)));
            p1.y = relu_f(fmaf(svA.z, ewA1, fmaf(svA.w, ewB1, eb1v)));
            p1.z = relu_f(fmaf(svB.x, ewA1, fmaf(svB.y, ewB1, eb1v)));
            p1.w = relu_f(fmaf(svB.z, ewA1, fmaf(svB.w, ewB1, eb1v)));
            buf4[jA*2 + eh]      = p0;
            buf4[(jA+32)*2 + eh] = p1;
        }

        const int rr[8] = {r01.x, r01.y, r01.z, r01.w, r2.x, r2.y, r2.z, r2.w};
        const int cc[8] = {c01.x, c01.y, c01.z, c01.w, c2.x, c2.y, c2.z, c2.w};

        float2 tpv[8];
        #pragma unroll
        for (int e = 0; e < 8; e++)
            tpv[e] = *(const float2*)(tp + (size_t)cc[e]*128 + 2*l);

        float t0[8], t1[8];
        #pragma unroll
        for (int e = 0; e < 8; e++) { t0[e] = b1a; t1[e] = b1b; }

        #pragma unroll 8
        for (int j2 = 0; j2 < 32; j2++) {
            float4 wq = gw1[j2*64 + l];
            float4 xa = buf4[(2*j2)*2 + 0];
            float4 xbv = buf4[(2*j2)*2 + 1];
            float4 xc = buf4[(2*j2+1)*2 + 0];
            float4 xd = buf4[(2*j2+1)*2 + 1];
            t0[0] = fmaf(xa.x, wq.x, fmaf(xc.x, wq.z, t0[0]));
            t1[0] = fmaf(xa.x, wq.y, fmaf(xc.x, wq.w, t1[0]));
            t0[1] = fmaf(xa.y, wq.x, fmaf(xc.y, wq.z, t0[1]));
            t1[1] = fmaf(xa.y, wq.y, fmaf(xc.y, wq.w, t1[1]));
            t0[2] = fmaf(xa.z, wq.x, fmaf(xc.z, wq.z, t0[2]));
            t1[2] = fmaf(xa.z, wq.y, fmaf(xc.z, wq.w, t1[2]));
            t0[3] = fmaf(xa.w, wq.x, fmaf(xc.w, wq.z, t0[3]));
            t1[3] = fmaf(xa.w, wq.y, fmaf(xc.w, wq.w, t1[3]));
            t0[4] = fmaf(xbv.x, wq.x, fmaf(xd.x, wq.z, t0[4]));
            t1[4] = fmaf(xbv.x, wq.y, fmaf(xd.x, wq.w, t1[4]));
            t0[5] = fmaf(xbv.y, wq.x, fmaf(xd.y, wq.z, t0[5]));
            t1[5] = fmaf(xbv.y, wq.y, fmaf(xd.y, wq.w, t1[5]));
            t0[6] = fmaf(xbv.z, wq.x, fmaf(xd.z, wq.z, t0[6]));
            t1[6] = fmaf(xbv.z, wq.y, fmaf(xd.z, wq.w, t1[6]));
            t0[7] = fmaf(xbv.w, wq.x, fmaf(xd.w, wq.z, t0[7]));
            t1[7] = fmaf(xbv.w, wq.y, fmaf(xd.w, wq.w, t1[7]));
        }

        // ---- pass A: h1 = relu(t + tp[col]) -> o1 -> jac1[col]
        #pragma unroll
        for (int e = 0; e < 8; e++) {
            *(float2*)(buf + e*128 + 2*l) =
                make_float2(relu_f(t0[e] + tpv[e].x), relu_f(t1[e] + tpv[e].y));
        }
        float2 tmv[8];
        #pragma unroll
        for (int e = 0; e < 8; e++)
            tmv[e] = *(const float2*)(tm + (size_t)rr[e]*128 + 2*l);

        float o1[8] = {0,0,0,0,0,0,0,0};
        #pragma unroll 8
        for (int k4 = 0; k4 < 32; k4++) {
            float4 wq = gw2[k4*64 + l];
            #pragma unroll
            for (int e = 0; e < 8; e++) {
                float4 hb = *(const float4*)(buf + e*128 + 4*k4);
                o1[e] = fmaf(hb.x, wq.x, fmaf(hb.y, wq.y,
                         fmaf(hb.z, wq.z, fmaf(hb.w, wq.w, o1[e]))));
            }
        }
        #pragma unroll
        for (int e = 0; e < 8; e++)
            atomicAdd(&jac1[(size_t)cc[e]*64 + l], o1[e] + b2r);

        // ---- pass B: h2 = relu(t + tm[row]) -> o2 -> jac2[row]
        #pragma unroll
        for (int e = 0; e < 8; e++) {
            *(float2*)(buf + e*128 + 2*l) =
                make_float2(relu_f(t0[e] + tmv[e].x), relu_f(t1[e] + tmv[e].y));
        }
        float o2[8] = {0,0,0,0,0,0,0,0};
        #pragma unroll 8
        for (int k4 = 0; k4 < 32; k4++) {
            float4 wq = gw2[k4*64 + l];
            #pragma unroll
            for (int e = 0; e < 8; e++) {
                float4 hb = *(const float4*)(buf + e*128 + 4*k4);
                o2[e] = fmaf(hb.x, wq.x, fmaf(hb.y, wq.y,
                         fmaf(hb.z, wq.z, fmaf(hb.w, wq.w, o2[e]))));
            }
        }
        #pragma unroll
        for (int e = 0; e < 8; e++)
            atomicAdd(&jac2[(size_t)rr[e]*64 + l], o2[e] + b2r);
    }
}

// ===========================================================================
// Node MLP kernels — weights streamed from global (coalesced, L1/L2-hot).
// ===========================================================================
__global__ __launch_bounds__(256, 4) void k_node_mlp(
    const float* __restrict__ A, const float* __restrict__ Bv,
    const float* __restrict__ sumsp,
    const float* __restrict__ e2w_g, const float* __restrict__ e2b_g,
    const float* __restrict__ W1g, const float* __restrict__ b1g,
    const float* __restrict__ W2g, const float* __restrict__ b2g,
    float* __restrict__ outp)
{
    extern __shared__ float lds[];                   // 4 waves * (768 + 512)
    const int wid = threadIdx.x >> 6, l = threadIdx.x & 63;
    float* xbuf = lds + wid * 768;
    float* hbuf = lds + 4*768 + wid * 512;

    const float ewl = e2w_g[l], ewl2 = e2w_g[64+l], ebl = e2b_g[l];
    const float bb0 = b1g[2*l], bb1 = b1g[2*l+1];
    const float bo = b2g[l];

    const int gw = blockIdx.x * 4 + wid;
    const int nw = gridDim.x * 4;

    for (int g = gw; g < BN/4; g += nw) {
        const int i0 = g * 4;
        float av[4], bv[4], iv[4];
        #pragma unroll
        for (int e = 0; e < 4; e++) {
            int i = i0 + e;
            av[e] = A[i*64 + l];
            bv[e] = Bv[i*64 + l];
            float q0 = inv_clean(sumsp[i*2+0]);
            float q1 = inv_clean(sumsp[i*2+1]);
            iv[e] = relu_f(fmaf(q0, ewl, fmaf(q1, ewl2, ebl)));
        }
        ((float4*)xbuf)[l]       = make_float4(av[0], av[1], av[2], av[3]);
        ((float4*)xbuf)[64 + l]  = make_float4(bv[0], bv[1], bv[2], bv[3]);
        ((float4*)xbuf)[128 + l] = make_float4(iv[0], iv[1], iv[2], iv[3]);

        float acc0[4] = {0,0,0,0}, acc1[4] = {0,0,0,0};
        #pragma unroll 8
        for (int j = 0; j < 192; j++) {
            float4 xv = ((const float4*)xbuf)[j];
            float2 wv = ((const float2*)(W1g + j*128))[l];
            acc0[0] = fmaf(xv.x, wv.x, acc0[0]);
            acc0[1] = fmaf(xv.y, wv.x, acc0[1]);
            acc0[2] = fmaf(xv.z, wv.x, acc0[2]);
            acc0[3] = fmaf(xv.w, wv.x, acc0[3]);
            acc1[0] = fmaf(xv.x, wv.y, acc1[0]);
            acc1[1] = fmaf(xv.y, wv.y, acc1[1]);
            acc1[2] = fmaf(xv.z, wv.y, acc1[2]);
            acc1[3] = fmaf(xv.w, wv.y, acc1[3]);
        }
        #pragma unroll
        for (int e = 0; e < 4; e++) {
            ((float2*)(hbuf + e*128))[l] = make_float2(relu_f(acc0[e]+bb0), relu_f(acc1[e]+bb1));
        }
        float o[4] = {0,0,0,0};
        #pragma unroll 8
        for (int k = 0; k < 128; k++) {
            float wv = W2g[k*64 + l];
            o[0] = fmaf(hbuf[0*128+k], wv, o[0]);
            o[1] = fmaf(hbuf[1*128+k], wv, o[1]);
            o[2] = fmaf(hbuf[2*128+k], wv, o[2]);
            o[3] = fmaf(hbuf[3*128+k], wv, o[3]);
        }
        #pragma unroll
        for (int e = 0; e < 4; e++) outp[(i0+e)*64 + l] = o[e] + bo;
    }
}

__global__ __launch_bounds__(256, 4) void k_node_final(
    const float* __restrict__ node_emb, const float* __restrict__ jacv,
    const float* __restrict__ hessv,
    const int* __restrict__ batch, const float* __restrict__ ga,
    const float* __restrict__ gw_g, const float* __restrict__ gb_g,
    const float* __restrict__ nW1, const float* __restrict__ nb1,
    const float* __restrict__ nW2, const float* __restrict__ nb2,
    const float* __restrict__ decW, const float* __restrict__ decb,
    const float* __restrict__ node_attr, float* __restrict__ outp)
{
    extern __shared__ float lds[];                   // 4 waves * (1024 + 512)
    const int wid = threadIdx.x >> 6, l = threadIdx.x & 63;
    float* xbuf = lds + wid * 1024;
    float* hbuf = lds + 4*1024 + wid * 512;

    const float gwl = gw_g[l], gwl2 = gw_g[64+l], gbl = gb_g[l];
    const float bb0 = nb1[2*l], bb1 = nb1[2*l+1];
    const float bo = nb2[l];

    const int gwv = blockIdx.x * 4 + wid;
    const int nw = gridDim.x * 4;

    for (int g = gwv; g < BN/4; g += nw) {
        const int i0 = g * 4;
        float ne[4], jv[4], ge[4], hv[4];
        #pragma unroll
        for (int e = 0; e < 4; e++) {
            int i = i0 + e;
            ne[e] = node_emb[i*64 + l];
            jv[e] = jacv[i*64 + l];
            hv[e] = hessv[i*64 + l];
            int gi = batch[i];
            ge[e] = relu_f(fmaf(ga[gi*2], gwl, fmaf(ga[gi*2+1], gwl2, gbl)));
        }
        ((float4*)xbuf)[l]       = make_float4(ne[0], ne[1], ne[2], ne[3]);
        ((float4*)xbuf)[64 + l]  = make_float4(jv[0], jv[1], jv[2], jv[3]);
        ((float4*)xbuf)[128 + l] = make_float4(ge[0], ge[1], ge[2], ge[3]);
        ((float4*)xbuf)[192 + l] = make_float4(hv[0], hv[1], hv[2], hv[3]);

        float acc0[4] = {0,0,0,0}, acc1[4] = {0,0,0,0};
        #pragma unroll 8
        for (int j = 0; j < 256; j++) {
            float4 xv = ((const float4*)xbuf)[j];
            float2 wv = ((const float2*)(nW1 + j*128))[l];
            acc0[0] = fmaf(xv.x, wv.x, acc0[0]);
            acc0[1] = fmaf(xv.y, wv.x, acc0[1]);
            acc0[2] = fmaf(xv.z, wv.x, acc0[2]);
            acc0[3] = fmaf(xv.w, wv.x, acc0[3]);
            acc1[0] = fmaf(xv.x, wv.y, acc1[0]);
            acc1[1] = fmaf(xv.y, wv.y, acc1[1]);
            acc1[2] = fmaf(xv.z, wv.y, acc1[2]);
            acc1[3] = fmaf(xv.w, wv.y, acc1[3]);
        }
        #pragma unroll
        for (int e = 0; e < 4; e++) {
            ((float2*)(hbuf + e*128))[l] = make_float2(relu_f(acc0[e]+bb0), relu_f(acc1[e]+bb1));
        }
        float o[4] = {0,0,0,0};
        #pragma unroll 8
        for (int k = 0; k < 128; k++) {
            float wv = nW2[k*64 + l];
            o[0] = fmaf(hbuf[0*128+k], wv, o[0]);
            o[1] = fmaf(hbuf[1*128+k], wv, o[1]);
            o[2] = fmaf(hbuf[2*128+k], wv, o[2]);
            o[3] = fmaf(hbuf[3*128+k], wv, o[3]);
        }
        #pragma unroll
        for (int e = 0; e < 4; e++) hbuf[e*128 + l] = o[e] + bo;

        int e2 = l >> 4, sub = l & 15, j2 = sub >> 3, part = sub & 7;
        float s = 0.0f;
        #pragma unroll
        for (int kk = 0; kk < 8; kk++) {
            int k = part*8 + kk;
            s = fmaf(hbuf[e2*128 + k], decW[k*2 + j2], s);
        }
        s += __shfl_xor(s, 1);
        s += __shfl_xor(s, 2);
        s += __shfl_xor(s, 4);
        if (part == 0) {
            int i = i0 + e2;
            outp[i*2 + j2] = (s + decb[j2]) * node_attr[i*2 + j2];
        }
    }
}

// ===========================================================================
// FALLBACK KERNELS (round-1 style, LDS-staged weights) — used only if ws too small
// ===========================================================================
__global__ __launch_bounds__(256) void k_edge1(
    const int* __restrict__ ei, const float* __restrict__ ea,
    const float* __restrict__ node_emb,
    const float* __restrict__ e2w_g, const float* __restrict__ e2b_g,
    const float* __restrict__ dW1, const float* __restrict__ db1,
    const float* __restrict__ dW2, const float* __restrict__ db2,
    float* __restrict__ sumsp, float* __restrict__ hjp, float* __restrict__ hjm)
{
    extern __shared__ float lds[];
    float* w1 = lds;
    float* b1 = w1 + 192*128;
    float* w2 = b1 + 128;
    float* b2 = w2 + 128*64;
    float* ew = b2 + 64;
    float* eb = ew + 128;
    float* xreg = eb + 64;
    float* hreg = xreg + 4*768;

    for (int idx = threadIdx.x; idx < 192*128; idx += 256) w1[idx] = dW1[idx];
    for (int idx = threadIdx.x; idx < 128*64; idx += 256)  w2[idx] = dW2[idx];
    if (threadIdx.x < 128) { b1[threadIdx.x] = db1[threadIdx.x]; ew[threadIdx.x] = e2w_g[threadIdx.x]; }
    if (threadIdx.x < 64)  { b2[threadIdx.x] = db2[threadIdx.x]; eb[threadIdx.x] = e2b_g[threadIdx.x]; }
    __syncthreads();

    const int wid = threadIdx.x >> 6, l = threadIdx.x & 63;
    float* xbuf = xreg + wid * 768;
    float* hbuf = hreg + wid * 512;
    const int gw = blockIdx.x * 4 + wid;
    const int nw = gridDim.x * 4;

    for (int g = gw; g < BE/4; g += nw) {
        const int e0 = g * 4;
        int r[4], c[4];
        float s0[4], s1[4];
        #pragma unroll
        for (int e = 0; e < 4; e++) {
            r[e]  = ei[e0+e];
            c[e]  = ei[BE + e0+e];
            s0[e] = ea[(e0+e)*2+0];
            s1[e] = ea[(e0+e)*2+1];
        }
        if (l < 16) {
            int e = l >> 2, wch = l & 3;
            int node = (wch < 2) ? r[e] : c[e];
            float v = (wch & 1) ? s1[e] : s0[e];
            atomicAdd(&sumsp[node*2 + (wch & 1)], v);
        }
        float ar[4], cr[4], ir[4];
        #pragma unroll
        for (int e = 0; e < 4; e++) {
            ar[e] = node_emb[r[e]*64 + l];
            cr[e] = node_emb[c[e]*64 + l];
            float q0 = inv_clean(s0[e]), q1 = inv_clean(s1[e]);
            ir[e] = relu_f(fmaf(q0, ew[l], fmaf(q1, ew[64+l], eb[l])));
        }
        ((float4*)xbuf)[l]       = make_float4(ar[0], ar[1], ar[2], ar[3]);
        ((float4*)xbuf)[64 + l]  = make_float4(cr[0], cr[1], cr[2], cr[3]);
        ((float4*)xbuf)[128 + l] = make_float4(ir[0], ir[1], ir[2], ir[3]);

        float acc0[4] = {0,0,0,0}, acc1[4] = {0,0,0,0};
        #pragma unroll 8
        for (int j = 0; j < 192; j++) {
            float4 xv = ((const float4*)xbuf)[j];
            float2 wv = ((const float2*)(w1 + j*128))[l];
            acc0[0] = fmaf(xv.x, wv.x, acc0[0]);
            acc0[1] = fmaf(xv.y, wv.x, acc0[1]);
            acc0[2] = fmaf(xv.z, wv.x, acc0[2]);
            acc0[3] = fmaf(xv.w, wv.x, acc0[3]);
            acc1[0] = fmaf(xv.x, wv.y, acc1[0]);
            acc1[1] = fmaf(xv.y, wv.y, acc1[1]);
            acc1[2] = fmaf(xv.z, wv.y, acc1[2]);
            acc1[3] = fmaf(xv.w, wv.y, acc1[3]);
        }
        float bb0 = b1[2*l], bb1 = b1[2*l+1];
        #pragma unroll
        for (int e = 0; e < 4; e++) {
            float2 h = make_float2(relu_f(acc0[e]+bb0), relu_f(acc1[e]+bb1));
            ((float2*)(hbuf + e*128))[l] = h;
        }
        float o[4] = {0,0,0,0};
        #pragma unroll 8
        for (int k = 0; k < 128; k++) {
            float wv = w2[k*64 + l];
            o[0] = fmaf(hbuf[0*128+k], wv, o[0]);
            o[1] = fmaf(hbuf[1*128+k], wv, o[1]);
            o[2] = fmaf(hbuf[2*128+k], wv, o[2]);
            o[3] = fmaf(hbuf[3*128+k], wv, o[3]);
        }
        float bo = b2[l];
        #pragma unroll
        for (int e = 0; e < 4; e++) {
            float ov = o[e] + bo;
            atomicAdd(&hjp[r[e]*64 + l], ov);
            atomicAdd(&hjm[c[e]*64 + l], ov);
        }
    }
}

__global__ __launch_bounds__(256) void k_edge2(
    const int* __restrict__ ei, const float* __restrict__ ea,
    const float* __restrict__ hjp, const float* __restrict__ hjm,
    const float* __restrict__ eew_g, const float* __restrict__ eeb_g,
    const float* __restrict__ hW1, const float* __restrict__ hb1,
    const float* __restrict__ hW2, const float* __restrict__ hb2,
    float* __restrict__ jac1, float* __restrict__ jac2)
{
    extern __shared__ float lds[];
    float* w1 = lds;
    float* b1 = w1 + 128*128;
    float* w2 = b1 + 128;
    float* b2 = w2 + 128*64;
    float* ew = b2 + 64;
    float* eb = ew + 128;
    float* base = eb + 64;

    for (int idx = threadIdx.x; idx < 128*128; idx += 256) w1[idx] = hW1[idx];
    for (int idx = threadIdx.x; idx < 128*64; idx += 256)  w2[idx] = hW2[idx];
    if (threadIdx.x < 128) { b1[threadIdx.x] = hb1[threadIdx.x]; ew[threadIdx.x] = eew_g[threadIdx.x]; }
    if (threadIdx.x < 64)  { b2[threadIdx.x] = hb2[threadIdx.x]; eb[threadIdx.x] = eeb_g[threadIdx.x]; }
    __syncthreads();

    const int wid = threadIdx.x >> 6, l = threadIdx.x & 63;
    float* x1 = base + wid*2048;
    float* x2 = x1 + 512;
    float* h1 = x2 + 512;
    float* h2 = h1 + 512;
    const int gw = blockIdx.x * 4 + wid;
    const int nw = gridDim.x * 4;

    for (int g = gw; g < BE/4; g += nw) {
        const int e0 = g * 4;
        int r[4], c[4];
        float se[4], pa[4], pb[4];
        #pragma unroll
        for (int e = 0; e < 4; e++) {
            r[e] = ei[e0+e];
            c[e] = ei[BE + e0+e];
            float sp0 = ea[(e0+e)*2+0], sp1 = ea[(e0+e)*2+1];
            se[e] = relu_f(fmaf(sp0, ew[l], fmaf(sp1, ew[64+l], eb[l])));
            pa[e] = hjp[c[e]*64 + l];
            pb[e] = hjm[r[e]*64 + l];
        }
        ((float4*)x1)[l]      = make_float4(se[0], se[1], se[2], se[3]);
        ((float4*)x1)[64 + l] = make_float4(pa[0], pa[1], pa[2], pa[3]);
        ((float4*)x2)[l]      = make_float4(se[0], se[1], se[2], se[3]);
        ((float4*)x2)[64 + l] = make_float4(pb[0], pb[1], pb[2], pb[3]);

        float a0[4]={0,0,0,0}, a1[4]={0,0,0,0}, b0v[4]={0,0,0,0}, b1v[4]={0,0,0,0};
        #pragma unroll 8
        for (int j = 0; j < 128; j++) {
            float2 wv = ((const float2*)(w1 + j*128))[l];
            float4 xa = ((const float4*)x1)[j];
            float4 xb = ((const float4*)x2)[j];
            a0[0]=fmaf(xa.x,wv.x,a0[0]); a0[1]=fmaf(xa.y,wv.x,a0[1]);
            a0[2]=fmaf(xa.z,wv.x,a0[2]); a0[3]=fmaf(xa.w,wv.x,a0[3]);
            a1[0]=fmaf(xa.x,wv.y,a1[0]); a1[1]=fmaf(xa.y,wv.y,a1[1]);
            a1[2]=fmaf(xa.z,wv.y,a1[2]); a1[3]=fmaf(xa.w,wv.y,a1[3]);
            b0v[0]=fmaf(xb.x,wv.x,b0v[0]); b0v[1]=fmaf(xb.y,wv.x,b0v[1]);
            b0v[2]=fmaf(xb.z,wv.x,b0v[2]); b0v[3]=fmaf(xb.w,wv.x,b0v[3]);
            b1v[0]=fmaf(xb.x,wv.y,b1v[0]); b1v[1]=fmaf(xb.y,wv.y,b1v[1]);
            b1v[2]=fmaf(xb.z,wv.y,b1v[2]); b1v[3]=fmaf(xb.w,wv.y,b1v[3]);
        }
        float bb0 = b1[2*l], bb1 = b1[2*l+1];
        #pragma unroll
        for (int e = 0; e < 4; e++) {
            ((float2*)(h1 + e*128))[l] = make_float2(relu_f(a0[e]+bb0), relu_f(a1[e]+bb1));
            ((float2*)(h2 + e*128))[l] = make_float2(relu_f(b0v[e]+bb0), relu_f(b1v[e]+bb1));
        }
        float oA[4]={0,0,0,0}, oB[4]={0,0,0,0};
        #pragma unroll 8
        for (int k = 0; k < 128; k++) {
            float wv = w2[k*64 + l];
            oA[0]=fmaf(h1[0*128+k],wv,oA[0]); oA[1]=fmaf(h1[1*128+k],wv,oA[1]);
            oA[2]=fmaf(h1[2*128+k],wv,oA[2]); oA[3]=fmaf(h1[3*128+k],wv,oA[3]);
            oB[0]=fmaf(h2[0*128+k],wv,oB[0]); oB[1]=fmaf(h2[1*128+k],wv,oB[1]);
            oB[2]=fmaf(h2[2*128+k],wv,oB[2]); oB[3]=fmaf(h2[3*128+k],wv,oB[3]);
        }
        float bo = b2[l];
        #pragma unroll
        for (int e = 0; e < 4; e++) {
            atomicAdd(&jac1[c[e]*64 + l], oA[e] + bo);
            atomicAdd(&jac2[r[e]*64 + l], oB[e] + bo);
        }
    }
}

// ===========================================================================
extern "C" void kernel_launch(void* const* d_in, const int* in_sizes, int n_in,
                              void* d_out, int out_size, void* d_ws, size_t ws_size,
                              hipStream_t stream) {
    const float* x          = (const float*)d_in[0];
    const int*   ei         = (const int*)  d_in[1];
    const int*   batch      = (const int*)  d_in[2];
    const float* node_attr  = (const float*)d_in[3];
    const float* edge_attr  = (const float*)d_in[4];
    const float* glob_attr  = (const float*)d_in[5];
    const float* enc_node_W = (const float*)d_in[6];
    const float* enc_node_b = (const float*)d_in[7];
    const float* enc_edge_W = (const float*)d_in[8];
    const float* enc_edge_b = (const float*)d_in[9];
    const float* enc_glob_W = (const float*)d_in[10];
    const float* enc_glob_b = (const float*)d_in[11];
    const float* enc2_W     = (const float*)d_in[12];
    const float* enc2_b     = (const float*)d_in[13];
    const float* dW1 = (const float*)d_in[14]; const float* db1 = (const float*)d_in[15];
    const float* dW2 = (const float*)d_in[16]; const float* db2 = (const float*)d_in[17];
    const float* hW1 = (const float*)d_in[18]; const float* hb1 = (const float*)d_in[19];
    const float* hW2 = (const float*)d_in[20]; const float* hb2 = (const float*)d_in[21];
    const float* jW1 = (const float*)d_in[22]; const float* jb1 = (const float*)d_in[23];
    const float* jW2 = (const float*)d_in[24]; const float* jb2 = (const float*)d_in[25];
    const float* sW1 = (const float*)d_in[26]; const float* sb1 = (const float*)d_in[27];
    const float* sW2 = (const float*)d_in[28]; const float* sb2 = (const float*)d_in[29];
    const float* nW1 = (const float*)d_in[30]; const float* nb1 = (const float*)d_in[31];
    const float* nW2 = (const float*)d_in[32]; const float* nb2 = (const float*)d_in[33];
    const float* decW = (const float*)d_in[34]; const float* decb = (const float*)d_in[35];

    float* ws = (float*)d_ws;
    const size_t NEED_FAST = 28900000ull * sizeof(float);   // 115.6 MB

    if (ws_size >= NEED_FAST) {
        // -------- fast path: linear-split pipeline, global packed weights ----
        float* ne    = ws;                      // 3.2M
        float* u     = ne + 3200000;            // 6.4M  (later tp)
        float* v     = u + 6400000;             // 6.4M  (later tm)
        float* hjp   = v + 6400000;             // 3.2M  (later hess)
        float* hjm   = hjp + 3200000;           // 3.2M
        float* jac1  = hjm + 3200000;           // 3.2M  (later jac)
        float* jac2  = jac1 + 3200000;          // 3.2M
        float* sumsp = jac2 + 3200000;          // 100K

        // packed weights live in the head of d_out (57,344 f <= out_size
        // 100,000 f). k_node_final fully overwrites d_out at the end.
        float* scratch = (float*)d_out;
        float4* puv   = (float4*)(scratch);             // 16384 f
        float4* pw1e1 = (float4*)(scratch + 16384);     // 8192 f
        float4* pw2e1 = (float4*)(scratch + 24576);     // 8192 f
        float4* pw1tp = (float4*)(scratch + 32768);     // 8192 f
        float4* pw1e2 = (float4*)(scratch + 40960);     // 8192 f
        float4* pw2e2 = (float4*)(scratch + 49152);     // 8192 f

        hipMemsetAsync(hjp, 0, (size_t)4*3200000*sizeof(float), stream);
        hipMemsetAsync(sumsp, 0, (size_t)100000*sizeof(float), stream);

        k_pack_uv<<<16, 256, 0, stream>>>(dW1, puv);
        k_pack_w1<<<8, 256, 0, stream>>>(dW1, 128, pw1e1);
        k_pack_w2<<<8, 256, 0, stream>>>(dW2, pw2e1);
        k_pack_w1<<<8, 256, 0, stream>>>(hW1, 64, pw1tp);
        k_pack_w1<<<8, 256, 0, stream>>>(hW1, 0, pw1e2);
        k_pack_w2<<<8, 256, 0, stream>>>(hW2, pw2e2);

        k_node_enc<<<12500, 256, 0, stream>>>(x, enc_node_W, enc_node_b, ne);

        k_uv<<<1536, 256, 2048*4, stream>>>(ne, puv, u, v);

        k_edge1f<<<1536, 256, 4096*4, stream>>>(ei, edge_attr, u, v, enc2_W, enc2_b,
                                                pw1e1, db1, pw2e1, db2, sumsp, hjp, hjm);

        k_tptm<<<1536, 256, 2048*4, stream>>>(hjp, hjm, pw1tp, u, v);  // tp->u, tm->v

        k_edge2f<<<1536, 256, 4096*4, stream>>>(ei, edge_attr, u, v,
                                                enc_edge_W, enc_edge_b,
                                                pw1e2, hb1, pw2e2, hb2, jac1, jac2);

        size_t lds_nm = (4*768 + 4*512) * sizeof(float);   // 20 KB
        k_node_mlp<<<1024, 256, lds_nm, stream>>>(jac1, jac2, sumsp, enc2_W, enc2_b,
                                                  jW1, jb1, jW2, jb2, jac1);
        k_node_mlp<<<1024, 256, lds_nm, stream>>>(hjp, hjm, sumsp, enc2_W, enc2_b,
                                                  sW1, sb1, sW2, sb2, hjp);

        size_t lds_nf = (4*1024 + 4*512) * sizeof(float);  // 24 KB
        k_node_final<<<1024, 256, lds_nf, stream>>>(ne, jac1, hjp,
                                                    batch, glob_attr, enc_glob_W, enc_glob_b,
                                                    nW1, nb1, nW2, nb2, decW, decb,
                                                    node_attr, (float*)d_out);
    } else {
        // -------- fallback: round-1 pipeline (64.4 MB) --------
        float* node_emb = ws;
        float* hjp   = node_emb + 3200000;
        float* hjm   = hjp + 3200000;
        float* jac1  = hjm + 3200000;
        float* jac2  = jac1 + 3200000;
        float* sumsp = jac2 + 3200000;

        hipMemsetAsync(hjp, 0, (size_t)4*3200000*sizeof(float), stream);
        hipMemsetAsync(sumsp, 0, (size_t)100000*sizeof(float), stream);

        k_node_enc<<<12500, 256, 0, stream>>>(x, enc_node_W, enc_node_b, node_emb);

        size_t lds1 = 38272u * sizeof(float);
        k_edge1<<<256, 256, lds1, stream>>>(ei, edge_attr, node_emb, enc2_W, enc2_b,
                                            dW1, db1, dW2, db2, sumsp, hjp, hjm);

        size_t lds2 = 33152u * sizeof(float);
        k_edge2<<<256, 256, lds2, stream>>>(ei, edge_attr, hjp, hjm,
                                            enc_edge_W, enc_edge_b,
                                            hW1, hb1, hW2, hb2, jac1, jac2);

        size_t lds_nm = (4*768 + 4*512) * sizeof(float);
        k_node_mlp<<<1024, 256, lds_nm, stream>>>(jac1, jac2, sumsp, enc2_W, enc2_b,
                                                  jW1, jb1, jW2, jb2, jac1);
        k_node_mlp<<<1024, 256, lds_nm, stream>>>(hjp, hjm, sumsp, enc2_W, enc2_b,
                                                  sW1, sb1, sW2, sb2, hjp);

        size_t lds_nf = (4*1024 + 4*512) * sizeof(float);
        k_node_final<<<1024, 256, lds_nf, stream>>>(node_emb, jac1, hjp,
                                                    batch, glob_attr, enc_glob_W, enc_glob_b,
                                                    nW1, nb1, nW2, nb2, decW, decb,
                                                    node_attr, (float*)d_out);
    }
}